// Round 2
// baseline (731.344 us; speedup 1.0000x reference)
//
#include <hip/hip_runtime.h>

#define N_    8192
#define T_    20
#define M_    6
#define D_    9
#define NM_   (N_*M_)        // 49152 LSTM chains
#define NT_   (N_*T_)        // 163840 GNN problems
#define NTM7_ (N_*T_*M_*7)   // 6881280 elements per output tensor

// overflow-safe fp32 sigmoid/tanh via hardware v_exp
__device__ __forceinline__ float sigm(float x){ return 1.f/(1.f + __expf(-x)); }
__device__ __forceinline__ float tanh_(float x){ return 2.f/(1.f + __expf(-2.f*x)) - 1.f; }

// ---------------------------------------------------------------------------
// Kernel 1: GNN (2x GRU message passing) + p0 readout. One thread per (n,t).
// Writes hidden [nm][t][d] fp32 to ws, pred_label0 fp32 to d_out + NTM7_.
// ---------------------------------------------------------------------------
__global__ __launch_bounds__(256) void k_gnn(
    const float* __restrict__ nf,    // (N,T,M,3)
    const float* __restrict__ pos,   // (N,T,M,6)
    const float* __restrict__ am,    // (N,T,M,M)
    const float* __restrict__ msgW, const float* __restrict__ msgb,
    const float* __restrict__ gWih, const float* __restrict__ gWhh,
    const float* __restrict__ gbih, const float* __restrict__ gbhh,
    const float* __restrict__ ro1W, const float* __restrict__ ro1b,
    const float* __restrict__ ro2W, const float* __restrict__ ro2b,
    const int*   __restrict__ numrec,
    float* __restrict__ hid,         // [nm][t][d] fp32
    float* __restrict__ out0)        // pred_label0 region
{
    int tid = blockIdx.x * blockDim.x + threadIdx.x;
    if (tid >= NT_) return;
    int n  = tid / T_;
    int t  = tid - n * T_;
    int nt = tid;

    // node_feat = concat(nodes_feature[n,t], pos[n,t]) -> s[m][0:9]
    float s[M_][D_];
    {
        const float2* p = (const float2*)nf + nt * 9;   // 18 floats, 8B-aligned
        #pragma unroll
        for (int j = 0; j < 9; ++j) {
            float2 v = p[j];
            int e0 = 2*j, e1 = 2*j + 1;                 // e = m*3 + c
            s[e0/3][e0%3] = v.x;
            s[e1/3][e1%3] = v.y;
        }
    }
    {
        const float4* p = (const float4*)pos + nt * 9;  // 36 floats, 16B-aligned
        #pragma unroll
        for (int j = 0; j < 9; ++j) {
            float4 v = p[j];
            int e = 4*j;                                // e = m*6 + c
            s[(e+0)/6][3 + (e+0)%6] = v.x;
            s[(e+1)/6][3 + (e+1)%6] = v.y;
            s[(e+2)/6][3 + (e+2)%6] = v.z;
            s[(e+3)/6][3 + (e+3)%6] = v.w;
        }
    }
    float att[M_][M_];
    {
        const float4* p = (const float4*)am + nt * 9;   // 36 floats, 16B-aligned
        #pragma unroll
        for (int j = 0; j < 9; ++j) {
            float4 v = p[j];
            int e = 4*j;                                // e = i*6 + q
            att[(e+0)/6][(e+0)%6] = v.x;
            att[(e+1)/6][(e+1)%6] = v.y;
            att[(e+2)/6][(e+2)%6] = v.z;
            att[(e+3)/6][(e+3)%6] = v.w;
        }
    }
    // valid mask uses num_rec[:, 0] only (reference: num_rec[:, 0:1])
    int nr = numrec[n * T_];
    float vm[M_];
    #pragma unroll
    for (int q = 0; q < M_; ++q) vm[q] = (q < nr) ? 1.f : 0.f;
    #pragma unroll
    for (int i = 0; i < M_; ++i)
        #pragma unroll
        for (int q = 0; q < M_; ++q) att[i][q] *= vm[q];

    // two GRU message-passing iterations (src = hv = s)
    #pragma unroll
    for (int it = 0; it < 2; ++it) {
        float msg[M_][D_];
        #pragma unroll
        for (int q = 0; q < M_; ++q) {
            #pragma unroll
            for (int d = 0; d < D_; ++d) {
                float a = msgb[d];
                #pragma unroll
                for (int k = 0; k < D_; ++k) a += s[q][k] * msgW[d*9 + k];
                msg[q][d] = a;
            }
        }
        #pragma unroll
        for (int i = 0; i < M_; ++i) {
            float mm[D_];
            #pragma unroll
            for (int d = 0; d < D_; ++d) {
                float a = att[i][0] * msg[0][d];
                #pragma unroll
                for (int q = 1; q < M_; ++q) a += att[i][q] * msg[q][d];
                mm[d] = a;
            }
            float gx[27], gh[27];
            #pragma unroll
            for (int g = 0; g < 27; ++g) {
                float ax = gbih[g];
                float ah = gbhh[g];
                #pragma unroll
                for (int k = 0; k < D_; ++k) {
                    ax += mm[k]   * gWih[g*9 + k];
                    ah += s[i][k] * gWhh[g*9 + k];
                }
                gx[g] = ax; gh[g] = ah;
            }
            #pragma unroll
            for (int d = 0; d < D_; ++d) {
                float r  = sigm(gx[d]       + gh[d]);
                float z  = sigm(gx[9 + d]   + gh[9 + d]);
                float nn = tanh_(gx[18 + d] + r * gh[18 + d]);
                s[i][d] = vm[i] * ((1.f - z) * nn + z * s[i][d]);
            }
        }
    }

    // hidden -> ws, layout [nm][t][d]
    float* hp = hid + (size_t)(n * M_) * (T_ * D_) + t * D_;
    #pragma unroll
    for (int i = 0; i < M_; ++i)
        #pragma unroll
        for (int d = 0; d < D_; ++d)
            hp[i * (T_ * D_) + d] = s[i][d];

    // p0 = (relu(h @ ro1^T + b1) @ ro2^T + b2) * vmask
    float pl[42];
    #pragma unroll
    for (int i = 0; i < M_; ++i) {
        float q9[D_];
        #pragma unroll
        for (int d = 0; d < D_; ++d) {
            float a = ro1b[d];
            #pragma unroll
            for (int k = 0; k < D_; ++k) a += s[i][k] * ro1W[d*9 + k];
            q9[d] = fmaxf(a, 0.f);
        }
        #pragma unroll
        for (int j = 0; j < 7; ++j) {
            float a = ro2b[j];
            #pragma unroll
            for (int k = 0; k < D_; ++k) a += q9[k] * ro2W[j*9 + k];
            pl[i*7 + j] = a * vm[i];
        }
    }
    // 42 contiguous fp32 per (n,t): 21 float2 stores (nt*168B is 8B-aligned)
    float2* op = (float2*)(out0) + nt * 21;
    #pragma unroll
    for (int j = 0; j < 21; ++j)
        op[j] = make_float2(pl[2*j], pl[2*j + 1]);
}

// ---------------------------------------------------------------------------
// Kernel 2: bidirectional LSTM over T + final readout. One thread per (n,m).
// ---------------------------------------------------------------------------
__device__ __forceinline__ void lstm_step(
    const float x[9], float h[9], float c[9],
    const float* __restrict__ Wih, const float* __restrict__ Whh,
    const float* __restrict__ bih, const float* __restrict__ bhh)
{
    float g[36];
    #pragma unroll
    for (int j = 0; j < 36; ++j) {
        float a = bih[j] + bhh[j];
        #pragma unroll
        for (int k = 0; k < 9; ++k) a += x[k] * Wih[j*9 + k];
        #pragma unroll
        for (int k = 0; k < 9; ++k) a += h[k] * Whh[j*9 + k];
        g[j] = a;
    }
    #pragma unroll
    for (int d = 0; d < 9; ++d) {
        float ii = sigm(g[d]);
        float ff = sigm(g[9 + d]);
        float gg = tanh_(g[18 + d]);
        float oo = sigm(g[27 + d]);
        float cc = ff * c[d] + ii * gg;
        c[d] = cc;
        h[d] = oo * tanh_(cc);
    }
}

__global__ __launch_bounds__(256) void k_lstm(
    const float* __restrict__ hid,     // [nm][t][d]
    float*       __restrict__ hfw,     // [nm][t][d] forward hidden states
    const float* __restrict__ lfWih, const float* __restrict__ lfWhh,
    const float* __restrict__ lfbih, const float* __restrict__ lfbhh,
    const float* __restrict__ lbWih, const float* __restrict__ lbWhh,
    const float* __restrict__ lbbih, const float* __restrict__ lbbhh,
    const float* __restrict__ lr1W, const float* __restrict__ lr1b,
    const float* __restrict__ lr2W, const float* __restrict__ lr2b,
    const int*   __restrict__ numrec,
    float* __restrict__ out)           // pred_label region (start of d_out)
{
    int nm = blockIdx.x * blockDim.x + threadIdx.x;
    if (nm >= NM_) return;
    int n = nm / M_;
    int m = nm - n * M_;
    const float* xb = hid + (size_t)nm * (T_ * D_);
    float*       hf = hfw + (size_t)nm * (T_ * D_);

    float h[9], c[9];
    #pragma unroll
    for (int d = 0; d < 9; ++d) { h[d] = 0.f; c[d] = 0.f; }
    // forward scan
    for (int t = 0; t < T_; ++t) {
        float x[9];
        #pragma unroll
        for (int k = 0; k < 9; ++k) x[k] = xb[t*9 + k];
        lstm_step(x, h, c, lfWih, lfWhh, lfbih, lfbhh);
        #pragma unroll
        for (int d = 0; d < 9; ++d) hf[t*9 + d] = h[d];
    }
    // backward scan + fused readout (hb[t] = h right after consuming x[t])
    #pragma unroll
    for (int d = 0; d < 9; ++d) { h[d] = 0.f; c[d] = 0.f; }
    float vi = (m < numrec[n * T_]) ? 1.f : 0.f;
    for (int t = T_ - 1; t >= 0; --t) {
        float x[9];
        #pragma unroll
        for (int k = 0; k < 9; ++k) x[k] = xb[t*9 + k];
        lstm_step(x, h, c, lbWih, lbWhh, lbbih, lbbhh);

        float q9[9];
        #pragma unroll
        for (int d = 0; d < 9; ++d) {
            float a = lr1b[d];
            #pragma unroll
            for (int k = 0; k < 9; ++k) a += hf[t*9 + k] * lr1W[d*18 + k];
            #pragma unroll
            for (int k = 0; k < 9; ++k) a += h[k]        * lr1W[d*18 + 9 + k];
            q9[d] = fmaxf(a, 0.f);
        }
        size_t ob = (size_t)((n * T_ + t) * M_ + m) * 7;
        #pragma unroll
        for (int j = 0; j < 7; ++j) {
            float a = lr2b[j];
            #pragma unroll
            for (int k = 0; k < 9; ++k) a += q9[k] * lr2W[j*9 + k];
            out[ob + j] = a * vi;
        }
    }
}

extern "C" void kernel_launch(void* const* d_in, const int* in_sizes, int n_in,
                              void* d_out, int out_size, void* d_ws, size_t ws_size,
                              hipStream_t stream) {
    const float* nf    = (const float*)d_in[0];
    const float* pos   = (const float*)d_in[1];
    const float* am    = (const float*)d_in[2];
    const float* msgW  = (const float*)d_in[3];
    const float* msgb  = (const float*)d_in[4];
    const float* gWih  = (const float*)d_in[5];
    const float* gWhh  = (const float*)d_in[6];
    const float* gbih  = (const float*)d_in[7];
    const float* gbhh  = (const float*)d_in[8];
    const float* ro1W  = (const float*)d_in[9];
    const float* ro1b  = (const float*)d_in[10];
    const float* ro2W  = (const float*)d_in[11];
    const float* ro2b  = (const float*)d_in[12];
    const float* lfWih = (const float*)d_in[13];
    const float* lfWhh = (const float*)d_in[14];
    const float* lfbih = (const float*)d_in[15];
    const float* lfbhh = (const float*)d_in[16];
    const float* lbWih = (const float*)d_in[17];
    const float* lbWhh = (const float*)d_in[18];
    const float* lbbih = (const float*)d_in[19];
    const float* lbbhh = (const float*)d_in[20];
    const float* lr1W  = (const float*)d_in[21];
    const float* lr1b  = (const float*)d_in[22];
    const float* lr2W  = (const float*)d_in[23];
    const float* lr2b  = (const float*)d_in[24];
    const int* numrec  = (const int*)d_in[25];

    // workspace: hidden [nm][t][d] fp32 + hf [nm][t][d] fp32 = 70,778,880 B
    float* hid = (float*)d_ws;
    float* hfw = hid + (size_t)NM_ * (T_ * D_);

    float* outp = (float*)d_out;           // pred_label
    float* out0 = (float*)d_out + NTM7_;   // pred_label0

    k_gnn <<<NT_ / 256, 256, 0, stream>>>(nf, pos, am, msgW, msgb, gWih, gWhh,
                                          gbih, gbhh, ro1W, ro1b, ro2W, ro2b,
                                          numrec, hid, out0);
    k_lstm<<<NM_ / 256, 256, 0, stream>>>(hid, hfw, lfWih, lfWhh, lfbih, lfbhh,
                                          lbWih, lbWhh, lbbih, lbbhh,
                                          lr1W, lr1b, lr2W, lr2b, numrec, outp);
}

// Round 3
// 419.403 us; speedup vs baseline: 1.7438x; 1.7438x over previous
//
#include <hip/hip_runtime.h>

#define N_    8192
#define T_    20
#define M_    6
#define D_    9
#define NM_   (N_*M_)        // 49152 LSTM chains
#define NT_   (N_*T_)        // 163840 GNN problems
#define NTM7_ (N_*T_*M_*7)   // 6881280 elements per output tensor

__device__ __forceinline__ float sigm(float x){ return 1.f/(1.f + __expf(-x)); }
__device__ __forceinline__ float tanh_(float x){ return 2.f/(1.f + __expf(-2.f*x)) - 1.f; }
__device__ __forceinline__ float shfl_(float v, int src){ return __shfl(v, src, 64); }

// ---------------------------------------------------------------------------
// Kernel A: GNN, one LANE per (n,t,node). 6 lanes per (n,t) group, 10 groups
// per wave (lanes 60..63 idle). msg exchanged across group via shuffles.
// Writes hidden [nm][t][d] fp32 to ws and pred_label0 to d_out + NTM7_.
// ---------------------------------------------------------------------------
__global__ __launch_bounds__(256) void k_gnn(
    const float* __restrict__ nf,    // (N,T,M,3)
    const float* __restrict__ pos,   // (N,T,M,6)
    const float* __restrict__ am,    // (N,T,M,M)
    const float* __restrict__ msgW, const float* __restrict__ msgb,
    const float* __restrict__ gWih, const float* __restrict__ gWhh,
    const float* __restrict__ gbih, const float* __restrict__ gbhh,
    const float* __restrict__ ro1W, const float* __restrict__ ro1b,
    const float* __restrict__ ro2W, const float* __restrict__ ro2b,
    const int*   __restrict__ numrec,
    float* __restrict__ hid,         // [nm][t][d]
    float* __restrict__ out0)        // pred_label0 region
{
    const int lane = threadIdx.x & 63;
    const int wib  = threadIdx.x >> 6;        // wave in block (0..3)
    const int g    = lane / 6;                // group in wave (0..9 valid)
    const int i    = lane - g * 6;            // node index 0..5
    const int gbase = g * 6;                  // first lane of my group
    const bool lactive = (lane < 60);

    int ntIdx = (blockIdx.x * 4 + wib) * 10 + g;
    const bool active = lactive && (ntIdx < NT_);
    const int nt = active ? ntIdx : 0;        // clamp for safe loads
    const int n  = nt / T_;
    const int t  = nt - n * T_;

    // own node features: concat(nodes_feature, pos)
    float s[D_];
    {
        const float* p = nf + (size_t)nt * 18 + i * 3;
        s[0] = p[0]; s[1] = p[1]; s[2] = p[2];
    }
    {
        const float* p = pos + (size_t)nt * 36 + i * 6;
        #pragma unroll
        for (int k = 0; k < 6; ++k) s[3 + k] = p[k];
    }
    // own attention row, masked by valid(q)
    float attr[M_];
    {
        const float* p = am + (size_t)nt * 36 + i * 6;
        #pragma unroll
        for (int q = 0; q < M_; ++q) attr[q] = p[q];
    }
    const int nr = numrec[n * T_];
    #pragma unroll
    for (int q = 0; q < M_; ++q) attr[q] *= (q < nr) ? 1.f : 0.f;
    const float vmi = (i < nr) ? 1.f : 0.f;

    // two GRU message-passing iterations
    #pragma unroll
    for (int it = 0; it < 2; ++it) {
        float msg[D_];
        #pragma unroll
        for (int d = 0; d < D_; ++d) {
            float a = msgb[d];
            #pragma unroll
            for (int k = 0; k < D_; ++k) a += s[k] * msgW[d*9 + k];
            msg[d] = a;
        }
        float mm[D_];
        #pragma unroll
        for (int d = 0; d < D_; ++d) {
            float a = 0.f;
            #pragma unroll
            for (int q = 0; q < M_; ++q) a += attr[q] * shfl_(msg[d], gbase + q);
            mm[d] = a;
        }
        float gx[27], gh[27];
        #pragma unroll
        for (int j = 0; j < 27; ++j) {
            float ax = gbih[j], ah = gbhh[j];
            #pragma unroll
            for (int k = 0; k < D_; ++k) {
                ax += mm[k] * gWih[j*9 + k];
                ah += s[k]  * gWhh[j*9 + k];
            }
            gx[j] = ax; gh[j] = ah;
        }
        #pragma unroll
        for (int d = 0; d < D_; ++d) {
            float r  = sigm(gx[d]       + gh[d]);
            float z  = sigm(gx[9 + d]   + gh[9 + d]);
            float nn = tanh_(gx[18 + d] + r * gh[18 + d]);
            s[d] = vmi * ((1.f - z) * nn + z * s[d]);
        }
    }

    // hidden -> ws [nm][t][d]
    if (active) {
        float* hp = hid + (size_t)(n * M_ + i) * (T_ * D_) + t * D_;
        #pragma unroll
        for (int d = 0; d < D_; ++d) hp[d] = s[d];
    }

    // p0 readout for own node
    float q9[D_];
    #pragma unroll
    for (int d = 0; d < D_; ++d) {
        float a = ro1b[d];
        #pragma unroll
        for (int k = 0; k < D_; ++k) a += s[k] * ro1W[d*9 + k];
        q9[d] = fmaxf(a, 0.f);
    }
    if (active) {
        float* op = out0 + (size_t)nt * 42 + i * 7;
        #pragma unroll
        for (int j = 0; j < 7; ++j) {
            float a = ro2b[j];
            #pragma unroll
            for (int k = 0; k < D_; ++k) a += q9[k] * ro2W[j*9 + k];
            op[j] = a * vmi;
        }
    }
}

// ---------------------------------------------------------------------------
// Kernel B: forward LSTM, one LANE per (chain, d). 9 lanes/chain, 7 chains
// per wave (lane 63 idle). Gate-row weights live in per-lane VGPRs.
// ---------------------------------------------------------------------------
__global__ __launch_bounds__(256) void k_lfwd(
    const float* __restrict__ hid,   // [nm][t][d]
    float*       __restrict__ hfw,   // [nm][t][d]
    const float* __restrict__ Wih, const float* __restrict__ Whh,
    const float* __restrict__ bih, const float* __restrict__ bhh)
{
    const int lane = threadIdx.x & 63;
    const int wib  = threadIdx.x >> 6;
    const int grp  = lane / 9;                // 0..6 valid
    const int d    = lane - grp * 9;
    const int gb   = grp * 9;
    bool active = (lane < 63);

    int ci = (blockIdx.x * 4 + wib) * 7 + grp;
    active = active && (ci < NM_);
    const int nm = active ? ci : 0;

    // own gate rows: i=d, f=9+d, g=18+d, o=27+d
    float wxi[9], wxf[9], wxg[9], wxo[9], whi[9], whf[9], whg[9], who[9];
    #pragma unroll
    for (int k = 0; k < 9; ++k) {
        wxi[k] = Wih[(d     )*9 + k];  whi[k] = Whh[(d     )*9 + k];
        wxf[k] = Wih[(9  + d)*9 + k];  whf[k] = Whh[(9  + d)*9 + k];
        wxg[k] = Wih[(18 + d)*9 + k];  whg[k] = Whh[(18 + d)*9 + k];
        wxo[k] = Wih[(27 + d)*9 + k];  who[k] = Whh[(27 + d)*9 + k];
    }
    const float bi = bih[d]      + bhh[d];
    const float bf = bih[9 + d]  + bhh[9 + d];
    const float bg = bih[18 + d] + bhh[18 + d];
    const float bo = bih[27 + d] + bhh[27 + d];

    const float* xb = hid + (size_t)nm * (T_ * D_);
    float*       hf = hfw + (size_t)nm * (T_ * D_);

    float h = 0.f, c = 0.f;
    for (int t = 0; t < T_; ++t) {
        const float x = xb[t*9 + d];
        float gi = bi, gf = bf, gg = bg, go = bo;
        #pragma unroll
        for (int j = 0; j < 9; ++j) {
            const float xj = shfl_(x, gb + j);
            const float hj = shfl_(h, gb + j);
            gi += xj * wxi[j]; gi += hj * whi[j];
            gf += xj * wxf[j]; gf += hj * whf[j];
            gg += xj * wxg[j]; gg += hj * whg[j];
            go += xj * wxo[j]; go += hj * who[j];
        }
        const float ii = sigm(gi), ff = sigm(gf), g2 = tanh_(gg), oo = sigm(go);
        c = ff * c + ii * g2;
        h = oo * tanh_(c);
        if (active) hf[t*9 + d] = h;
    }
}

// ---------------------------------------------------------------------------
// Kernel C: backward LSTM + fused final readout. Same lane mapping as B.
// hb never touches memory; reads hf written by kernel B.
// ---------------------------------------------------------------------------
__global__ __launch_bounds__(256) void k_lbwd(
    const float* __restrict__ hid,   // [nm][t][d]
    const float* __restrict__ hfw,   // [nm][t][d]
    const float* __restrict__ Wih, const float* __restrict__ Whh,
    const float* __restrict__ bih, const float* __restrict__ bhh,
    const float* __restrict__ lr1W, const float* __restrict__ lr1b,
    const float* __restrict__ lr2W, const float* __restrict__ lr2b,
    const int*   __restrict__ numrec,
    float* __restrict__ out)         // pred_label region
{
    const int lane = threadIdx.x & 63;
    const int wib  = threadIdx.x >> 6;
    const int grp  = lane / 9;
    const int d    = lane - grp * 9;
    const int gb   = grp * 9;
    bool active = (lane < 63);

    int ci = (blockIdx.x * 4 + wib) * 7 + grp;
    active = active && (ci < NM_);
    const int nm = active ? ci : 0;
    const int n  = nm / M_;
    const int m  = nm - n * M_;

    float wxi[9], wxf[9], wxg[9], wxo[9], whi[9], whf[9], whg[9], who[9];
    #pragma unroll
    for (int k = 0; k < 9; ++k) {
        wxi[k] = Wih[(d     )*9 + k];  whi[k] = Whh[(d     )*9 + k];
        wxf[k] = Wih[(9  + d)*9 + k];  whf[k] = Whh[(9  + d)*9 + k];
        wxg[k] = Wih[(18 + d)*9 + k];  whg[k] = Whh[(18 + d)*9 + k];
        wxo[k] = Wih[(27 + d)*9 + k];  who[k] = Whh[(27 + d)*9 + k];
    }
    const float bi = bih[d]      + bhh[d];
    const float bf = bih[9 + d]  + bhh[9 + d];
    const float bg = bih[18 + d] + bhh[18 + d];
    const float bo = bih[27 + d] + bhh[27 + d];

    // readout weights: lane d owns lr1W row d (hf half + hb half), lr2W row d (d<7)
    float w1f[9], w1b[9], w2[9];
    #pragma unroll
    for (int k = 0; k < 9; ++k) {
        w1f[k] = lr1W[d*18 + k];
        w1b[k] = lr1W[d*18 + 9 + k];
        w2[k]  = lr2W[(d < 7 ? d : 6)*9 + k];
    }
    const float b1 = lr1b[d];
    const float b2 = lr2b[d < 7 ? d : 6];
    const float vi = (m < numrec[n * T_]) ? 1.f : 0.f;

    const float* xb = hid + (size_t)nm * (T_ * D_);
    const float* hf = hfw + (size_t)nm * (T_ * D_);

    float h = 0.f, c = 0.f;
    for (int tt = T_ - 1; tt >= 0; --tt) {
        const float x = xb[tt*9 + d];
        float gi = bi, gf = bf, gg = bg, go = bo;
        #pragma unroll
        for (int j = 0; j < 9; ++j) {
            const float xj = shfl_(x, gb + j);
            const float hj = shfl_(h, gb + j);
            gi += xj * wxi[j]; gi += hj * whi[j];
            gf += xj * wxf[j]; gf += hj * whf[j];
            gg += xj * wxg[j]; gg += hj * whg[j];
            go += xj * wxo[j]; go += hj * who[j];
        }
        const float ii = sigm(gi), ff = sigm(gf), g2 = tanh_(gg), oo = sigm(go);
        c = ff * c + ii * g2;
        h = oo * tanh_(c);                       // hb[tt] for my d

        // fused readout: q[d] = relu(b1 + hf.w1f + hb.w1b), then
        // out[j] = b2 + sum_dd q[dd]*lr2W[j][dd]  (lane j<7 stores)
        const float hfv = hf[tt*9 + d];
        float q = b1;
        #pragma unroll
        for (int j = 0; j < 9; ++j) {
            q += shfl_(hfv, gb + j) * w1f[j];
            q += shfl_(h,   gb + j) * w1b[j];
        }
        q = fmaxf(q, 0.f);
        float o = b2;
        #pragma unroll
        for (int dd = 0; dd < 9; ++dd) o += shfl_(q, gb + dd) * w2[dd];
        if (active && d < 7)
            out[(size_t)((n * T_ + tt) * M_ + m) * 7 + d] = o * vi;
    }
}

extern "C" void kernel_launch(void* const* d_in, const int* in_sizes, int n_in,
                              void* d_out, int out_size, void* d_ws, size_t ws_size,
                              hipStream_t stream) {
    const float* nf    = (const float*)d_in[0];
    const float* pos   = (const float*)d_in[1];
    const float* am    = (const float*)d_in[2];
    const float* msgW  = (const float*)d_in[3];
    const float* msgb  = (const float*)d_in[4];
    const float* gWih  = (const float*)d_in[5];
    const float* gWhh  = (const float*)d_in[6];
    const float* gbih  = (const float*)d_in[7];
    const float* gbhh  = (const float*)d_in[8];
    const float* ro1W  = (const float*)d_in[9];
    const float* ro1b  = (const float*)d_in[10];
    const float* ro2W  = (const float*)d_in[11];
    const float* ro2b  = (const float*)d_in[12];
    const float* lfWih = (const float*)d_in[13];
    const float* lfWhh = (const float*)d_in[14];
    const float* lfbih = (const float*)d_in[15];
    const float* lfbhh = (const float*)d_in[16];
    const float* lbWih = (const float*)d_in[17];
    const float* lbWhh = (const float*)d_in[18];
    const float* lbbih = (const float*)d_in[19];
    const float* lbbhh = (const float*)d_in[20];
    const float* lr1W  = (const float*)d_in[21];
    const float* lr1b  = (const float*)d_in[22];
    const float* lr2W  = (const float*)d_in[23];
    const float* lr2b  = (const float*)d_in[24];
    const int* numrec  = (const int*)d_in[25];

    // ws: hidden [nm][t][d] + hf [nm][t][d], fp32 = 70,778,880 B
    float* hid = (float*)d_ws;
    float* hfw = hid + (size_t)NM_ * (T_ * D_);

    float* outp = (float*)d_out;           // pred_label
    float* out0 = (float*)d_out + NTM7_;   // pred_label0

    // A: 40 (n,t) per block -> 4096 blocks
    k_gnn <<<NT_ / 40, 256, 0, stream>>>(nf, pos, am, msgW, msgb, gWih, gWhh,
                                         gbih, gbhh, ro1W, ro1b, ro2W, ro2b,
                                         numrec, hid, out0);
    // B/C: 28 chains per block -> ceil(49152/28) = 1756 blocks
    const int lgrid = (NM_ + 27) / 28;
    k_lfwd<<<lgrid, 256, 0, stream>>>(hid, hfw, lfWih, lfWhh, lfbih, lfbhh);
    k_lbwd<<<lgrid, 256, 0, stream>>>(hid, hfw, lbWih, lbWhh, lbbih, lbbhh,
                                      lr1W, lr1b, lr2W, lr2b, numrec, outp);
}

// Round 4
// 361.911 us; speedup vs baseline: 2.0208x; 1.1589x over previous
//
#include <hip/hip_runtime.h>

#define N_    8192
#define T_    20
#define M_    6
#define D_    9
#define NM_   (N_*M_)        // 49152 LSTM chains
#define NT_   (N_*T_)        // 163840 GNN problems
#define NTM7_ (N_*T_*M_*7)   // 6881280 elements per output tensor

#define LOG2E 1.44269504088896f

// native-rate activations: v_exp_f32 + v_rcp_f32 (no IEEE div sequence)
__device__ __forceinline__ float sigm(float x){
    return __builtin_amdgcn_rcpf(1.f + __builtin_amdgcn_exp2f(-LOG2E * x));
}
__device__ __forceinline__ float tanh_(float x){
    return fmaf(2.f, __builtin_amdgcn_rcpf(1.f + __builtin_amdgcn_exp2f(-2.f*LOG2E * x)), -1.f);
}
__device__ __forceinline__ float shfl_(float v, int src){ return __shfl(v, src, 64); }

// ---------------------------------------------------------------------------
// Kernel A: GNN, one LANE per (n,t,node). 6 lanes per (n,t) group, 10 groups
// per wave (lanes 60..63 idle). msg exchanged across group via shuffles.
// Writes hidden [nm][t][d] fp32 to ws and pred_label0 to d_out + NTM7_.
// ---------------------------------------------------------------------------
__global__ __launch_bounds__(256) void k_gnn(
    const float* __restrict__ nf,    // (N,T,M,3)
    const float* __restrict__ pos,   // (N,T,M,6)
    const float* __restrict__ am,    // (N,T,M,M)
    const float* __restrict__ msgW, const float* __restrict__ msgb,
    const float* __restrict__ gWih, const float* __restrict__ gWhh,
    const float* __restrict__ gbih, const float* __restrict__ gbhh,
    const float* __restrict__ ro1W, const float* __restrict__ ro1b,
    const float* __restrict__ ro2W, const float* __restrict__ ro2b,
    const int*   __restrict__ numrec,
    float* __restrict__ hid,         // [nm][t][d]
    float* __restrict__ out0)        // pred_label0 region
{
    const int lane = threadIdx.x & 63;
    const int wib  = threadIdx.x >> 6;        // wave in block (0..3)
    const int g    = lane / 6;                // group in wave (0..9 valid)
    const int i    = lane - g * 6;            // node index 0..5
    const int gbase = g * 6;                  // first lane of my group
    const bool lactive = (lane < 60);

    int ntIdx = (blockIdx.x * 4 + wib) * 10 + g;
    const bool active = lactive && (ntIdx < NT_);
    const int nt = active ? ntIdx : 0;        // clamp for safe loads
    const int n  = nt / T_;
    const int t  = nt - n * T_;

    // own node features: concat(nodes_feature, pos)
    float s[D_];
    {
        const float* p = nf + (size_t)nt * 18 + i * 3;
        s[0] = p[0]; s[1] = p[1]; s[2] = p[2];
    }
    {
        const float* p = pos + (size_t)nt * 36 + i * 6;
        #pragma unroll
        for (int k = 0; k < 6; ++k) s[3 + k] = p[k];
    }
    // own attention row, masked by valid(q)
    float attr[M_];
    {
        const float* p = am + (size_t)nt * 36 + i * 6;
        #pragma unroll
        for (int q = 0; q < M_; ++q) attr[q] = p[q];
    }
    const int nr = numrec[n * T_];
    #pragma unroll
    for (int q = 0; q < M_; ++q) attr[q] *= (q < nr) ? 1.f : 0.f;
    const float vmi = (i < nr) ? 1.f : 0.f;

    // two GRU message-passing iterations
    #pragma unroll
    for (int it = 0; it < 2; ++it) {
        float msg[D_];
        #pragma unroll
        for (int d = 0; d < D_; ++d) {
            float a = msgb[d];
            #pragma unroll
            for (int k = 0; k < D_; ++k) a += s[k] * msgW[d*9 + k];
            msg[d] = a;
        }
        float mm[D_];
        #pragma unroll
        for (int d = 0; d < D_; ++d) {
            float a = 0.f;
            #pragma unroll
            for (int q = 0; q < M_; ++q) a += attr[q] * shfl_(msg[d], gbase + q);
            mm[d] = a;
        }
        float gx[27], gh[27];
        #pragma unroll
        for (int j = 0; j < 27; ++j) {
            float ax = gbih[j], ah = gbhh[j];
            #pragma unroll
            for (int k = 0; k < D_; ++k) {
                ax += mm[k] * gWih[j*9 + k];
                ah += s[k]  * gWhh[j*9 + k];
            }
            gx[j] = ax; gh[j] = ah;
        }
        #pragma unroll
        for (int d = 0; d < D_; ++d) {
            float r  = sigm(gx[d]       + gh[d]);
            float z  = sigm(gx[9 + d]   + gh[9 + d]);
            float nn = tanh_(gx[18 + d] + r * gh[18 + d]);
            s[d] = vmi * ((1.f - z) * nn + z * s[d]);
        }
    }

    // hidden -> ws [nm][t][d]
    if (active) {
        float* hp = hid + (size_t)(n * M_ + i) * (T_ * D_) + t * D_;
        #pragma unroll
        for (int d = 0; d < D_; ++d) hp[d] = s[d];
    }

    // p0 readout for own node
    float q9[D_];
    #pragma unroll
    for (int d = 0; d < D_; ++d) {
        float a = ro1b[d];
        #pragma unroll
        for (int k = 0; k < D_; ++k) a += s[k] * ro1W[d*9 + k];
        q9[d] = fmaxf(a, 0.f);
    }
    if (active) {
        float* op = out0 + (size_t)nt * 42 + i * 7;
        #pragma unroll
        for (int j = 0; j < 7; ++j) {
            float a = ro2b[j];
            #pragma unroll
            for (int k = 0; k < D_; ++k) a += q9[k] * ro2W[j*9 + k];
            op[j] = a * vmi;
        }
    }
}

// ---------------------------------------------------------------------------
// Kernel B: merged bidirectional LSTM + fused readout. One LANE per (chain,d),
// 9 lanes/chain, 7 chains/wave (lane 63 idle). Forward hidden states live in
// a private LDS slot (20 floats/thread, no barriers needed).
// ---------------------------------------------------------------------------
__global__ __launch_bounds__(256) void k_lstm(
    const float* __restrict__ hid,   // [nm][t][d]
    const float* __restrict__ fWih, const float* __restrict__ fWhh,
    const float* __restrict__ fbih, const float* __restrict__ fbhh,
    const float* __restrict__ bWih, const float* __restrict__ bWhh,
    const float* __restrict__ bbih, const float* __restrict__ bbhh,
    const float* __restrict__ lr1W, const float* __restrict__ lr1b,
    const float* __restrict__ lr2W, const float* __restrict__ lr2b,
    const int*   __restrict__ numrec,
    float* __restrict__ out)         // pred_label region
{
    __shared__ float hfL[256 * T_];              // 20480 B, private slots
    float* myhf = &hfL[threadIdx.x * T_];

    const int lane = threadIdx.x & 63;
    const int wib  = threadIdx.x >> 6;
    const int grp  = lane / 9;                   // 0..6 valid
    const int d    = lane - grp * 9;
    const int gb   = grp * 9;
    bool active = (lane < 63);

    int ci = (blockIdx.x * 4 + wib) * 7 + grp;
    active = active && (ci < NM_);
    const int nm = active ? ci : 0;
    const int n  = nm / M_;
    const int m  = nm - n * M_;

    const float* xb = hid + (size_t)nm * (T_ * D_);

    // ---------------- forward phase ----------------
    {
        float wxi[9], wxf[9], wxg[9], wxo[9], whi[9], whf[9], whg[9], who[9];
        #pragma unroll
        for (int k = 0; k < 9; ++k) {
            wxi[k] = fWih[(d     )*9 + k];  whi[k] = fWhh[(d     )*9 + k];
            wxf[k] = fWih[(9  + d)*9 + k];  whf[k] = fWhh[(9  + d)*9 + k];
            wxg[k] = fWih[(18 + d)*9 + k];  whg[k] = fWhh[(18 + d)*9 + k];
            wxo[k] = fWih[(27 + d)*9 + k];  who[k] = fWhh[(27 + d)*9 + k];
        }
        const float bi = fbih[d]      + fbhh[d];
        const float bf = fbih[9 + d]  + fbhh[9 + d];
        const float bg = fbih[18 + d] + fbhh[18 + d];
        const float bo = fbih[27 + d] + fbhh[27 + d];

        float h = 0.f, c = 0.f;
        for (int t = 0; t < T_; ++t) {
            const float x = xb[t*9 + d];
            float gi = bi, gf = bf, gg = bg, go = bo;
            #pragma unroll
            for (int j = 0; j < 9; ++j) {
                const float xj = shfl_(x, gb + j);
                const float hj = shfl_(h, gb + j);
                gi += xj * wxi[j]; gi += hj * whi[j];
                gf += xj * wxf[j]; gf += hj * whf[j];
                gg += xj * wxg[j]; gg += hj * whg[j];
                go += xj * wxo[j]; go += hj * who[j];
            }
            c = sigm(gf) * c + sigm(gi) * tanh_(gg);
            h = sigm(go) * tanh_(c);
            myhf[t] = h;
        }
    }

    // ---------------- backward phase + fused readout ----------------
    {
        float wxi[9], wxf[9], wxg[9], wxo[9], whi[9], whf[9], whg[9], who[9];
        #pragma unroll
        for (int k = 0; k < 9; ++k) {
            wxi[k] = bWih[(d     )*9 + k];  whi[k] = bWhh[(d     )*9 + k];
            wxf[k] = bWih[(9  + d)*9 + k];  whf[k] = bWhh[(9  + d)*9 + k];
            wxg[k] = bWih[(18 + d)*9 + k];  whg[k] = bWhh[(18 + d)*9 + k];
            wxo[k] = bWih[(27 + d)*9 + k];  who[k] = bWhh[(27 + d)*9 + k];
        }
        const float bi = bbih[d]      + bbhh[d];
        const float bf = bbih[9 + d]  + bbhh[9 + d];
        const float bg = bbih[18 + d] + bbhh[18 + d];
        const float bo = bbih[27 + d] + bbhh[27 + d];

        // readout rows: lane d owns lr1 row d and lr2 row d (d<7)
        float w1f[9], w1b[9], w2[9];
        #pragma unroll
        for (int k = 0; k < 9; ++k) {
            w1f[k] = lr1W[d*18 + k];
            w1b[k] = lr1W[d*18 + 9 + k];
            w2[k]  = lr2W[(d < 7 ? d : 6)*9 + k];
        }
        const float b1 = lr1b[d];
        const float b2 = lr2b[d < 7 ? d : 6];
        const float vi = (m < numrec[n * T_]) ? 1.f : 0.f;

        float h = 0.f, c = 0.f;
        for (int tt = T_ - 1; tt >= 0; --tt) {
            const float x = xb[tt*9 + d];
            float gi = bi, gf = bf, gg = bg, go = bo;
            #pragma unroll
            for (int j = 0; j < 9; ++j) {
                const float xj = shfl_(x, gb + j);
                const float hj = shfl_(h, gb + j);
                gi += xj * wxi[j]; gi += hj * whi[j];
                gf += xj * wxf[j]; gf += hj * whf[j];
                gg += xj * wxg[j]; gg += hj * whg[j];
                go += xj * wxo[j]; go += hj * who[j];
            }
            c = sigm(gf) * c + sigm(gi) * tanh_(gg);
            h = sigm(go) * tanh_(c);              // hb[tt] for my d

            const float hfv = myhf[tt];
            float q = b1;
            #pragma unroll
            for (int j = 0; j < 9; ++j) {
                q += shfl_(hfv, gb + j) * w1f[j];
                q += shfl_(h,   gb + j) * w1b[j];
            }
            q = fmaxf(q, 0.f);
            float o = b2;
            #pragma unroll
            for (int dd = 0; dd < 9; ++dd) o += shfl_(q, gb + dd) * w2[dd];
            if (active && d < 7)
                out[(size_t)((n * T_ + tt) * M_ + m) * 7 + d] = o * vi;
        }
    }
}

extern "C" void kernel_launch(void* const* d_in, const int* in_sizes, int n_in,
                              void* d_out, int out_size, void* d_ws, size_t ws_size,
                              hipStream_t stream) {
    const float* nf    = (const float*)d_in[0];
    const float* pos   = (const float*)d_in[1];
    const float* am    = (const float*)d_in[2];
    const float* msgW  = (const float*)d_in[3];
    const float* msgb  = (const float*)d_in[4];
    const float* gWih  = (const float*)d_in[5];
    const float* gWhh  = (const float*)d_in[6];
    const float* gbih  = (const float*)d_in[7];
    const float* gbhh  = (const float*)d_in[8];
    const float* ro1W  = (const float*)d_in[9];
    const float* ro1b  = (const float*)d_in[10];
    const float* ro2W  = (const float*)d_in[11];
    const float* ro2b  = (const float*)d_in[12];
    const float* lfWih = (const float*)d_in[13];
    const float* lfWhh = (const float*)d_in[14];
    const float* lfbih = (const float*)d_in[15];
    const float* lfbhh = (const float*)d_in[16];
    const float* lbWih = (const float*)d_in[17];
    const float* lbWhh = (const float*)d_in[18];
    const float* lbbih = (const float*)d_in[19];
    const float* lbbhh = (const float*)d_in[20];
    const float* lr1W  = (const float*)d_in[21];
    const float* lr1b  = (const float*)d_in[22];
    const float* lr2W  = (const float*)d_in[23];
    const float* lr2b  = (const float*)d_in[24];
    const int* numrec  = (const int*)d_in[25];

    // ws: hidden [nm][t][d] fp32 = 35,389,440 B
    float* hid = (float*)d_ws;

    float* outp = (float*)d_out;           // pred_label
    float* out0 = (float*)d_out + NTM7_;   // pred_label0

    // A: 40 (n,t) per block -> 4096 blocks
    k_gnn <<<NT_ / 40, 256, 0, stream>>>(nf, pos, am, msgW, msgb, gWih, gWhh,
                                         gbih, gbhh, ro1W, ro1b, ro2W, ro2b,
                                         numrec, hid, out0);
    // B: 28 chains per block -> ceil(49152/28) = 1756 blocks
    const int lgrid = (NM_ + 27) / 28;
    k_lstm<<<lgrid, 256, 0, stream>>>(hid, lfWih, lfWhh, lfbih, lfbhh,
                                      lbWih, lbWhh, lbbih, lbbhh,
                                      lr1W, lr1b, lr2W, lr2b, numrec, outp);
}

// Round 6
// 329.712 us; speedup vs baseline: 2.2181x; 1.0977x over previous
//
#include <hip/hip_runtime.h>

#define N_    8192
#define T_    20
#define M_    6
#define D_    9
#define NM_   (N_*M_)        // 49152 LSTM chains
#define NT_   (N_*T_)        // 163840 GNN problems
#define NTM7_ (N_*T_*M_*7)   // 6881280 elements per output tensor

#define LOG2E 1.44269504088896f

// native-rate activations: v_exp_f32 + v_rcp_f32 (no IEEE div sequence)
__device__ __forceinline__ float sigm(float x){
    return __builtin_amdgcn_rcpf(1.f + __builtin_amdgcn_exp2f(-LOG2E * x));
}
__device__ __forceinline__ float tanh_(float x){
    return fmaf(2.f, __builtin_amdgcn_rcpf(1.f + __builtin_amdgcn_exp2f(-2.f*LOG2E * x)), -1.f);
}
__device__ __forceinline__ float shfl_(float v, int src){ return __shfl(v, src, 64); }

// ---------------------------------------------------------------------------
// Kernel A: GNN, one LANE per (n,t,node). 6 lanes per (n,t) group, 10 groups
// per wave (lanes 60..63 idle). msg exchanged across group via shuffles.
// (unchanged — verified at R4)
// ---------------------------------------------------------------------------
__global__ __launch_bounds__(256) void k_gnn(
    const float* __restrict__ nf,    // (N,T,M,3)
    const float* __restrict__ pos,   // (N,T,M,6)
    const float* __restrict__ am,    // (N,T,M,M)
    const float* __restrict__ msgW, const float* __restrict__ msgb,
    const float* __restrict__ gWih, const float* __restrict__ gWhh,
    const float* __restrict__ gbih, const float* __restrict__ gbhh,
    const float* __restrict__ ro1W, const float* __restrict__ ro1b,
    const float* __restrict__ ro2W, const float* __restrict__ ro2b,
    const int*   __restrict__ numrec,
    float* __restrict__ hid,         // [nm][t][d]
    float* __restrict__ out0)        // pred_label0 region
{
    const int lane = threadIdx.x & 63;
    const int wib  = threadIdx.x >> 6;        // wave in block (0..3)
    const int g    = lane / 6;                // group in wave (0..9 valid)
    const int i    = lane - g * 6;            // node index 0..5
    const int gbase = g * 6;                  // first lane of my group
    const bool lactive = (lane < 60);

    int ntIdx = (blockIdx.x * 4 + wib) * 10 + g;
    const bool active = lactive && (ntIdx < NT_);
    const int nt = active ? ntIdx : 0;        // clamp for safe loads
    const int n  = nt / T_;
    const int t  = nt - n * T_;

    // own node features: concat(nodes_feature, pos)
    float s[D_];
    {
        const float* p = nf + (size_t)nt * 18 + i * 3;
        s[0] = p[0]; s[1] = p[1]; s[2] = p[2];
    }
    {
        const float* p = pos + (size_t)nt * 36 + i * 6;
        #pragma unroll
        for (int k = 0; k < 6; ++k) s[3 + k] = p[k];
    }
    // own attention row, masked by valid(q)
    float attr[M_];
    {
        const float* p = am + (size_t)nt * 36 + i * 6;
        #pragma unroll
        for (int q = 0; q < M_; ++q) attr[q] = p[q];
    }
    const int nr = numrec[n * T_];
    #pragma unroll
    for (int q = 0; q < M_; ++q) attr[q] *= (q < nr) ? 1.f : 0.f;
    const float vmi = (i < nr) ? 1.f : 0.f;

    // two GRU message-passing iterations
    #pragma unroll
    for (int it = 0; it < 2; ++it) {
        float msg[D_];
        #pragma unroll
        for (int d = 0; d < D_; ++d) {
            float a = msgb[d];
            #pragma unroll
            for (int k = 0; k < D_; ++k) a += s[k] * msgW[d*9 + k];
            msg[d] = a;
        }
        float mm[D_];
        #pragma unroll
        for (int d = 0; d < D_; ++d) {
            float a = 0.f;
            #pragma unroll
            for (int q = 0; q < M_; ++q) a += attr[q] * shfl_(msg[d], gbase + q);
            mm[d] = a;
        }
        float gx[27], gh[27];
        #pragma unroll
        for (int j = 0; j < 27; ++j) {
            float ax = gbih[j], ah = gbhh[j];
            #pragma unroll
            for (int k = 0; k < D_; ++k) {
                ax += mm[k] * gWih[j*9 + k];
                ah += s[k]  * gWhh[j*9 + k];
            }
            gx[j] = ax; gh[j] = ah;
        }
        #pragma unroll
        for (int d = 0; d < D_; ++d) {
            float r  = sigm(gx[d]       + gh[d]);
            float z  = sigm(gx[9 + d]   + gh[9 + d]);
            float nn = tanh_(gx[18 + d] + r * gh[18 + d]);
            s[d] = vmi * ((1.f - z) * nn + z * s[d]);
        }
    }

    // hidden -> ws [nm][t][d]
    if (active) {
        float* hp = hid + (size_t)(n * M_ + i) * (T_ * D_) + t * D_;
        #pragma unroll
        for (int d = 0; d < D_; ++d) hp[d] = s[d];
    }

    // p0 readout for own node
    float q9[D_];
    #pragma unroll
    for (int d = 0; d < D_; ++d) {
        float a = ro1b[d];
        #pragma unroll
        for (int k = 0; k < D_; ++k) a += s[k] * ro1W[d*9 + k];
        q9[d] = fmaxf(a, 0.f);
    }
    if (active) {
        float* op = out0 + (size_t)nt * 42 + i * 7;
        #pragma unroll
        for (int j = 0; j < 7; ++j) {
            float a = ro2b[j];
            #pragma unroll
            for (int k = 0; k < D_; ++k) a += q9[k] * ro2W[j*9 + k];
            op[j] = a * vmi;
        }
    }
}

// ---------------------------------------------------------------------------
// Kernel B: merged bidirectional LSTM + deferred fused readout.
// 128 threads = 2 waves, 7 chains/wave, 9 lanes/chain; lane 63 of each wave
// gets a PRIVATE dummy LDS row (fixes R5's lane-63 corruption).
// Cross-lane exchange via wave-synchronous LDS broadcast rows; hf and hb are
// stored to LDS during the scans, readout runs as a separate wave-local phase
// (one (chain,t) item per lane) to minimize DS-pipe issue count.
//   hxs: [16 rows][20 dwords]   (h,x) float2 x9 + pad
//   hst: [16 rows][t*20 + d] hf at +0..8, hb at +10..18 (row stride 404)
// ---------------------------------------------------------------------------
#define CPB 14   // chains per block

__global__ __launch_bounds__(128) void k_lstm(
    const float* __restrict__ hid,   // [nm][t][d]
    const float* __restrict__ fWih, const float* __restrict__ fWhh,
    const float* __restrict__ fbih, const float* __restrict__ fbhh,
    const float* __restrict__ bWih, const float* __restrict__ bWhh,
    const float* __restrict__ bbih, const float* __restrict__ bbhh,
    const float* __restrict__ lr1W, const float* __restrict__ lr1b,
    const float* __restrict__ lr2W, const float* __restrict__ lr2b,
    const int*   __restrict__ numrec,
    float* __restrict__ out)         // pred_label region
{
    __shared__ float hst[16 * 404];  // 25856 B
    __shared__ float hxs[16 * 20];   //  1280 B

    const int lane = threadIdx.x & 63;
    const int wib  = threadIdx.x >> 6;         // 0..1
    const int grp0 = lane / 9;                 // 0..7 (7 == lane 63 only)
    const int d    = lane - grp0 * 9;
    const int row  = wib * 8 + grp0;           // LDS row; rows 7,15 are dummies
    const int grp  = (grp0 < 7) ? grp0 : 6;    // chain index for global mapping

    bool active = (lane < 63);
    int ci = blockIdx.x * CPB + wib * 7 + grp;
    active = active && (ci < NM_);
    const int nm = active ? ci : 0;

    const float* xb = hid + (size_t)nm * (T_ * D_);
    const int crow = row * 20;
    const int hrow = row * 404;

    // ---------------- forward scan ----------------
    {
        float wxi[9], wxf[9], wxg[9], wxo[9], whi[9], whf[9], whg[9], who[9];
        #pragma unroll
        for (int k = 0; k < 9; ++k) {
            wxi[k] = fWih[(d     )*9 + k];  whi[k] = fWhh[(d     )*9 + k];
            wxf[k] = fWih[(9  + d)*9 + k];  whf[k] = fWhh[(9  + d)*9 + k];
            wxg[k] = fWih[(18 + d)*9 + k];  whg[k] = fWhh[(18 + d)*9 + k];
            wxo[k] = fWih[(27 + d)*9 + k];  who[k] = fWhh[(27 + d)*9 + k];
        }
        const float bi = fbih[d]      + fbhh[d];
        const float bf = fbih[9 + d]  + fbhh[9 + d];
        const float bg = fbih[18 + d] + fbhh[18 + d];
        const float bo = fbih[27 + d] + fbhh[27 + d];

        hxs[crow + 2*d] = 0.f;                 // h(-1) = 0
        float h = 0.f, c = 0.f;
        for (int t = 0; t < T_; ++t) {
            hxs[crow + 2*d + 1] = xb[t*9 + d];           // publish x
            float gi = bi, gf = bf, gg = bg, go = bo;
            #pragma unroll
            for (int j = 0; j < 8; j += 2) {             // b128: (h,x,h,x)
                float4 v = *(const float4*)&hxs[crow + 2*j];
                gi = fmaf(v.x, whi[j], fmaf(v.y, wxi[j], gi));
                gf = fmaf(v.x, whf[j], fmaf(v.y, wxf[j], gf));
                gg = fmaf(v.x, whg[j], fmaf(v.y, wxg[j], gg));
                go = fmaf(v.x, who[j], fmaf(v.y, wxo[j], go));
                gi = fmaf(v.z, whi[j+1], fmaf(v.w, wxi[j+1], gi));
                gf = fmaf(v.z, whf[j+1], fmaf(v.w, wxf[j+1], gf));
                gg = fmaf(v.z, whg[j+1], fmaf(v.w, wxg[j+1], gg));
                go = fmaf(v.z, who[j+1], fmaf(v.w, wxo[j+1], go));
            }
            {
                float2 v = *(const float2*)&hxs[crow + 16];
                gi = fmaf(v.x, whi[8], fmaf(v.y, wxi[8], gi));
                gf = fmaf(v.x, whf[8], fmaf(v.y, wxf[8], gf));
                gg = fmaf(v.x, whg[8], fmaf(v.y, wxg[8], gg));
                go = fmaf(v.x, who[8], fmaf(v.y, wxo[8], go));
            }
            c = sigm(gf) * c + sigm(gi) * tanh_(gg);
            h = sigm(go) * tanh_(c);
            hst[hrow + t*20 + d] = h;                    // save hf[t]
            hxs[crow + 2*d] = h;                         // publish h for t+1
        }
    }

    // ---------------- backward scan ----------------
    {
        float wxi[9], wxf[9], wxg[9], wxo[9], whi[9], whf[9], whg[9], who[9];
        #pragma unroll
        for (int k = 0; k < 9; ++k) {
            wxi[k] = bWih[(d     )*9 + k];  whi[k] = bWhh[(d     )*9 + k];
            wxf[k] = bWih[(9  + d)*9 + k];  whf[k] = bWhh[(9  + d)*9 + k];
            wxg[k] = bWih[(18 + d)*9 + k];  whg[k] = bWhh[(18 + d)*9 + k];
            wxo[k] = bWih[(27 + d)*9 + k];  who[k] = bWhh[(27 + d)*9 + k];
        }
        const float bi = bbih[d]      + bbhh[d];
        const float bf = bbih[9 + d]  + bbhh[9 + d];
        const float bg = bbih[18 + d] + bbhh[18 + d];
        const float bo = bbih[27 + d] + bbhh[27 + d];

        hxs[crow + 2*d] = 0.f;                 // hb(T) = 0
        float h = 0.f, c = 0.f;
        for (int tt = T_ - 1; tt >= 0; --tt) {
            hxs[crow + 2*d + 1] = xb[tt*9 + d];          // publish x
            float gi = bi, gf = bf, gg = bg, go = bo;
            #pragma unroll
            for (int j = 0; j < 8; j += 2) {
                float4 v = *(const float4*)&hxs[crow + 2*j];
                gi = fmaf(v.x, whi[j], fmaf(v.y, wxi[j], gi));
                gf = fmaf(v.x, whf[j], fmaf(v.y, wxf[j], gf));
                gg = fmaf(v.x, whg[j], fmaf(v.y, wxg[j], gg));
                go = fmaf(v.x, who[j], fmaf(v.y, wxo[j], go));
                gi = fmaf(v.z, whi[j+1], fmaf(v.w, wxi[j+1], gi));
                gf = fmaf(v.z, whf[j+1], fmaf(v.w, wxf[j+1], gf));
                gg = fmaf(v.z, whg[j+1], fmaf(v.w, wxg[j+1], gg));
                go = fmaf(v.z, who[j+1], fmaf(v.w, wxo[j+1], go));
            }
            {
                float2 v = *(const float2*)&hxs[crow + 16];
                gi = fmaf(v.x, whi[8], fmaf(v.y, wxi[8], gi));
                gf = fmaf(v.x, whf[8], fmaf(v.y, wxf[8], gf));
                gg = fmaf(v.x, whg[8], fmaf(v.y, wxg[8], gg));
                go = fmaf(v.x, who[8], fmaf(v.y, wxo[8], go));
            }
            c = sigm(gf) * c + sigm(gi) * tanh_(gg);
            h = sigm(go) * tanh_(c);                     // hb[tt]
            hst[hrow + tt*20 + 10 + d] = h;              // save hb[tt]
            hxs[crow + 2*d] = h;                         // publish for tt-1
        }
    }

    // ---------------- deferred readout (wave-local items) ----------------
    // 140 items per wave: item -> (chain 0..6, t 0..19)
    #pragma unroll 1
    for (int rr = 0; rr < 3; ++rr) {
        const int item = rr * 64 + lane;
        if (item >= 140) break;
        const int ch = item / 20;
        const int t  = item - ch * 20;
        const int ci2 = blockIdx.x * CPB + wib * 7 + ch;
        if (ci2 >= NM_) continue;
        const int base = (wib * 8 + ch) * 404 + t * 20;

        float hf[9], hb[9];
        #pragma unroll
        for (int j = 0; j < 4; ++j) {
            float2 a = *(const float2*)&hst[base + 2*j];
            hf[2*j] = a.x; hf[2*j+1] = a.y;
            float2 b = *(const float2*)&hst[base + 10 + 2*j];
            hb[2*j] = b.x; hb[2*j+1] = b.y;
        }
        hf[8] = hst[base + 8];
        hb[8] = hst[base + 18];

        const int n2 = ci2 / M_;
        const int m2 = ci2 - n2 * M_;
        const float vi = (m2 < numrec[n2 * T_]) ? 1.f : 0.f;

        float q[9];
        #pragma unroll
        for (int dd = 0; dd < 9; ++dd) {
            float a = lr1b[dd];
            #pragma unroll
            for (int k = 0; k < 9; ++k) a = fmaf(hf[k], lr1W[dd*18 + k], a);
            #pragma unroll
            for (int k = 0; k < 9; ++k) a = fmaf(hb[k], lr1W[dd*18 + 9 + k], a);
            q[dd] = fmaxf(a, 0.f);
        }
        float* op = out + (size_t)((n2 * T_ + t) * M_ + m2) * 7;
        #pragma unroll
        for (int j = 0; j < 7; ++j) {
            float a = lr2b[j];
            #pragma unroll
            for (int k = 0; k < 9; ++k) a = fmaf(q[k], lr2W[j*9 + k], a);
            op[j] = a * vi;
        }
    }
}

extern "C" void kernel_launch(void* const* d_in, const int* in_sizes, int n_in,
                              void* d_out, int out_size, void* d_ws, size_t ws_size,
                              hipStream_t stream) {
    const float* nf    = (const float*)d_in[0];
    const float* pos   = (const float*)d_in[1];
    const float* am    = (const float*)d_in[2];
    const float* msgW  = (const float*)d_in[3];
    const float* msgb  = (const float*)d_in[4];
    const float* gWih  = (const float*)d_in[5];
    const float* gWhh  = (const float*)d_in[6];
    const float* gbih  = (const float*)d_in[7];
    const float* gbhh  = (const float*)d_in[8];
    const float* ro1W  = (const float*)d_in[9];
    const float* ro1b  = (const float*)d_in[10];
    const float* ro2W  = (const float*)d_in[11];
    const float* ro2b  = (const float*)d_in[12];
    const float* lfWih = (const float*)d_in[13];
    const float* lfWhh = (const float*)d_in[14];
    const float* lfbih = (const float*)d_in[15];
    const float* lfbhh = (const float*)d_in[16];
    const float* lbWih = (const float*)d_in[17];
    const float* lbWhh = (const float*)d_in[18];
    const float* lbbih = (const float*)d_in[19];
    const float* lbbhh = (const float*)d_in[20];
    const float* lr1W  = (const float*)d_in[21];
    const float* lr1b  = (const float*)d_in[22];
    const float* lr2W  = (const float*)d_in[23];
    const float* lr2b  = (const float*)d_in[24];
    const int* numrec  = (const int*)d_in[25];

    // ws: hidden [nm][t][d] fp32 = 35,389,440 B
    float* hid = (float*)d_ws;

    float* outp = (float*)d_out;           // pred_label
    float* out0 = (float*)d_out + NTM7_;   // pred_label0

    // A: 40 (n,t) per block -> 4096 blocks
    k_gnn <<<NT_ / 40, 256, 0, stream>>>(nf, pos, am, msgW, msgb, gWih, gWhh,
                                         gbih, gbhh, ro1W, ro1b, ro2W, ro2b,
                                         numrec, hid, out0);
    // B: 14 chains per 128-thread block
    const int lgrid = (NM_ + CPB - 1) / CPB;
    k_lstm<<<lgrid, 128, 0, stream>>>(hid, lfWih, lfWhh, lfbih, lfbhh,
                                      lbWih, lbWhh, lbbih, lbbhh,
                                      lr1W, lr1b, lr2W, lr2b, numrec, outp);
}

// Round 7
// 323.204 us; speedup vs baseline: 2.2628x; 1.0201x over previous
//
#include <hip/hip_runtime.h>

#define N_    8192
#define T_    20
#define M_    6
#define D_    9
#define NM_   (N_*M_)        // 49152 LSTM chains
#define NT_   (N_*T_)        // 163840 GNN problems
#define NTM7_ (N_*T_*M_*7)   // 6881280 elements per output tensor

#define LOG2E 1.44269504088896f

typedef __attribute__((ext_vector_type(2))) float v2f;

// native-rate activations: v_exp_f32 + v_rcp_f32 (no IEEE div sequence)
__device__ __forceinline__ float sigm(float x){
    return __builtin_amdgcn_rcpf(1.f + __builtin_amdgcn_exp2f(-LOG2E * x));
}
__device__ __forceinline__ float tanh_(float x){
    return fmaf(2.f, __builtin_amdgcn_rcpf(1.f + __builtin_amdgcn_exp2f(-2.f*LOG2E * x)), -1.f);
}
__device__ __forceinline__ float shfl_(float v, int src){ return __shfl(v, src, 64); }
__device__ __forceinline__ v2f splat(float s){ return (v2f){s, s}; }
__device__ __forceinline__ v2f shfl2(v2f v, int src){
    v2f r; r.x = __shfl(v.x, src, 64); r.y = __shfl(v.y, src, 64); return r;
}
__device__ __forceinline__ v2f sigm2(v2f x){ v2f r; r.x = sigm(x.x); r.y = sigm(x.y); return r; }
__device__ __forceinline__ v2f tanh2(v2f x){ v2f r; r.x = tanh_(x.x); r.y = tanh_(x.y); return r; }
__device__ __forceinline__ v2f relu2(v2f x){ v2f r; r.x = fmaxf(x.x,0.f); r.y = fmaxf(x.y,0.f); return r; }

// ---------------------------------------------------------------------------
// Kernel A: GNN with packed-fp32 (v_pk_fma_f32) — TWO (n,t) problems per lane
// in float2 SIMD. 6 lanes per problem-pair group, 10 groups/wave (lanes 60..63
// idle). Wave covers 20 problems: group g owns (base+g, base+10+g).
// ---------------------------------------------------------------------------
__global__ __launch_bounds__(256) void k_gnn(
    const float* __restrict__ nf,    // (N,T,M,3)
    const float* __restrict__ pos,   // (N,T,M,6)
    const float* __restrict__ am,    // (N,T,M,M)
    const float* __restrict__ msgW, const float* __restrict__ msgb,
    const float* __restrict__ gWih, const float* __restrict__ gWhh,
    const float* __restrict__ gbih, const float* __restrict__ gbhh,
    const float* __restrict__ ro1W, const float* __restrict__ ro1b,
    const float* __restrict__ ro2W, const float* __restrict__ ro2b,
    const int*   __restrict__ numrec,
    float* __restrict__ hid,         // [nm][t][d]
    float* __restrict__ out0)        // pred_label0 region
{
    const int lane = threadIdx.x & 63;
    const int wib  = threadIdx.x >> 6;        // wave in block (0..3)
    const int g    = lane / 6;                // group in wave (0..9 valid)
    const int i    = lane - g * 6;            // node index 0..5
    const int gbase = g * 6;
    const bool lactive = (lane < 60);

    const int wbase = (blockIdx.x * 4 + wib) * 20;   // NT_ divisible by 20
    const int ntA = wbase + g;                       // always < NT_
    const int ntB = wbase + 10 + g;
    const int nA = ntA / T_, tA = ntA - nA * T_;
    const int nB = ntB / T_, tB = ntB - nB * T_;

    // own node features: concat(nodes_feature, pos), packed A/B
    v2f s[D_];
    {
        const float* pA = nf + (size_t)ntA * 18 + i * 3;
        const float* pB = nf + (size_t)ntB * 18 + i * 3;
        #pragma unroll
        for (int k = 0; k < 3; ++k) { s[k].x = pA[k]; s[k].y = pB[k]; }
    }
    {
        const float* pA = pos + (size_t)ntA * 36 + i * 6;
        const float* pB = pos + (size_t)ntB * 36 + i * 6;
        #pragma unroll
        for (int k = 0; k < 6; ++k) { s[3+k].x = pA[k]; s[3+k].y = pB[k]; }
    }
    v2f attr[M_];
    {
        const float* pA = am + (size_t)ntA * 36 + i * 6;
        const float* pB = am + (size_t)ntB * 36 + i * 6;
        #pragma unroll
        for (int q = 0; q < M_; ++q) { attr[q].x = pA[q]; attr[q].y = pB[q]; }
    }
    const int nrA = numrec[nA * T_];
    const int nrB = numrec[nB * T_];
    #pragma unroll
    for (int q = 0; q < M_; ++q) {
        attr[q].x *= (q < nrA) ? 1.f : 0.f;
        attr[q].y *= (q < nrB) ? 1.f : 0.f;
    }
    v2f vmi; vmi.x = (i < nrA) ? 1.f : 0.f; vmi.y = (i < nrB) ? 1.f : 0.f;

    // two GRU message-passing iterations (packed)
    #pragma unroll
    for (int it = 0; it < 2; ++it) {
        v2f msg[D_];
        #pragma unroll
        for (int d = 0; d < D_; ++d) {
            v2f a = splat(msgb[d]);
            #pragma unroll
            for (int k = 0; k < D_; ++k) a += s[k] * msgW[d*9 + k];
            msg[d] = a;
        }
        v2f mm[D_];
        #pragma unroll
        for (int d = 0; d < D_; ++d) {
            v2f a = splat(0.f);
            #pragma unroll
            for (int q = 0; q < M_; ++q) a += attr[q] * shfl2(msg[d], gbase + q);
            mm[d] = a;
        }
        // j<18: r,z need only gx+gh sum -> single accumulator
        v2f grz[18], gxn[9], ghn[9];
        #pragma unroll
        for (int j = 0; j < 18; ++j) {
            v2f a = splat(gbih[j] + gbhh[j]);
            #pragma unroll
            for (int k = 0; k < D_; ++k) {
                a += mm[k] * gWih[j*9 + k];
                a += s[k]  * gWhh[j*9 + k];
            }
            grz[j] = a;
        }
        #pragma unroll
        for (int j = 0; j < 9; ++j) {
            v2f ax = splat(gbih[18 + j]), ah = splat(gbhh[18 + j]);
            #pragma unroll
            for (int k = 0; k < D_; ++k) {
                ax += mm[k] * gWih[(18 + j)*9 + k];
                ah += s[k]  * gWhh[(18 + j)*9 + k];
            }
            gxn[j] = ax; ghn[j] = ah;
        }
        #pragma unroll
        for (int d = 0; d < D_; ++d) {
            v2f r  = sigm2(grz[d]);
            v2f z  = sigm2(grz[9 + d]);
            v2f nn = tanh2(gxn[d] + r * ghn[d]);
            s[d] = vmi * ((splat(1.f) - z) * nn + z * s[d]);
        }
    }

    // hidden -> ws [nm][t][d]
    if (lactive) {
        float* hpA = hid + (size_t)(nA * M_ + i) * (T_ * D_) + tA * D_;
        float* hpB = hid + (size_t)(nB * M_ + i) * (T_ * D_) + tB * D_;
        #pragma unroll
        for (int d = 0; d < D_; ++d) { hpA[d] = s[d].x; hpB[d] = s[d].y; }
    }

    // p0 readout
    v2f q9[D_];
    #pragma unroll
    for (int d = 0; d < D_; ++d) {
        v2f a = splat(ro1b[d]);
        #pragma unroll
        for (int k = 0; k < D_; ++k) a += s[k] * ro1W[d*9 + k];
        q9[d] = relu2(a);
    }
    if (lactive) {
        float* opA = out0 + (size_t)ntA * 42 + i * 7;
        float* opB = out0 + (size_t)ntB * 42 + i * 7;
        #pragma unroll
        for (int j = 0; j < 7; ++j) {
            v2f a = splat(ro2b[j]);
            #pragma unroll
            for (int k = 0; k < D_; ++k) a += q9[k] * ro2W[j*9 + k];
            a *= vmi;
            opA[j] = a.x; opB[j] = a.y;
        }
    }
}

// ---------------------------------------------------------------------------
// Kernel B: merged bidirectional LSTM + deferred fused readout.
// (unchanged — verified at R6)
// ---------------------------------------------------------------------------
#define CPB 14   // chains per block

__global__ __launch_bounds__(128) void k_lstm(
    const float* __restrict__ hid,   // [nm][t][d]
    const float* __restrict__ fWih, const float* __restrict__ fWhh,
    const float* __restrict__ fbih, const float* __restrict__ fbhh,
    const float* __restrict__ bWih, const float* __restrict__ bWhh,
    const float* __restrict__ bbih, const float* __restrict__ bbhh,
    const float* __restrict__ lr1W, const float* __restrict__ lr1b,
    const float* __restrict__ lr2W, const float* __restrict__ lr2b,
    const int*   __restrict__ numrec,
    float* __restrict__ out)         // pred_label region
{
    __shared__ float hst[16 * 404];  // 25856 B
    __shared__ float hxs[16 * 20];   //  1280 B

    const int lane = threadIdx.x & 63;
    const int wib  = threadIdx.x >> 6;         // 0..1
    const int grp0 = lane / 9;                 // 0..7 (7 == lane 63 only)
    const int d    = lane - grp0 * 9;
    const int row  = wib * 8 + grp0;           // LDS row; rows 7,15 are dummies
    const int grp  = (grp0 < 7) ? grp0 : 6;    // chain index for global mapping

    bool active = (lane < 63);
    int ci = blockIdx.x * CPB + wib * 7 + grp;
    active = active && (ci < NM_);
    const int nm = active ? ci : 0;

    const float* xb = hid + (size_t)nm * (T_ * D_);
    const int crow = row * 20;
    const int hrow = row * 404;

    // ---------------- forward scan ----------------
    {
        float wxi[9], wxf[9], wxg[9], wxo[9], whi[9], whf[9], whg[9], who[9];
        #pragma unroll
        for (int k = 0; k < 9; ++k) {
            wxi[k] = fWih[(d     )*9 + k];  whi[k] = fWhh[(d     )*9 + k];
            wxf[k] = fWih[(9  + d)*9 + k];  whf[k] = fWhh[(9  + d)*9 + k];
            wxg[k] = fWih[(18 + d)*9 + k];  whg[k] = fWhh[(18 + d)*9 + k];
            wxo[k] = fWih[(27 + d)*9 + k];  who[k] = fWhh[(27 + d)*9 + k];
        }
        const float bi = fbih[d]      + fbhh[d];
        const float bf = fbih[9 + d]  + fbhh[9 + d];
        const float bg = fbih[18 + d] + fbhh[18 + d];
        const float bo = fbih[27 + d] + fbhh[27 + d];

        hxs[crow + 2*d] = 0.f;                 // h(-1) = 0
        float h = 0.f, c = 0.f;
        for (int t = 0; t < T_; ++t) {
            hxs[crow + 2*d + 1] = xb[t*9 + d];           // publish x
            float gi = bi, gf = bf, gg = bg, go = bo;
            #pragma unroll
            for (int j = 0; j < 8; j += 2) {             // b128: (h,x,h,x)
                float4 v = *(const float4*)&hxs[crow + 2*j];
                gi = fmaf(v.x, whi[j], fmaf(v.y, wxi[j], gi));
                gf = fmaf(v.x, whf[j], fmaf(v.y, wxf[j], gf));
                gg = fmaf(v.x, whg[j], fmaf(v.y, wxg[j], gg));
                go = fmaf(v.x, who[j], fmaf(v.y, wxo[j], go));
                gi = fmaf(v.z, whi[j+1], fmaf(v.w, wxi[j+1], gi));
                gf = fmaf(v.z, whf[j+1], fmaf(v.w, wxf[j+1], gf));
                gg = fmaf(v.z, whg[j+1], fmaf(v.w, wxg[j+1], gg));
                go = fmaf(v.z, who[j+1], fmaf(v.w, wxo[j+1], go));
            }
            {
                float2 v = *(const float2*)&hxs[crow + 16];
                gi = fmaf(v.x, whi[8], fmaf(v.y, wxi[8], gi));
                gf = fmaf(v.x, whf[8], fmaf(v.y, wxf[8], gf));
                gg = fmaf(v.x, whg[8], fmaf(v.y, wxg[8], gg));
                go = fmaf(v.x, who[8], fmaf(v.y, wxo[8], go));
            }
            c = sigm(gf) * c + sigm(gi) * tanh_(gg);
            h = sigm(go) * tanh_(c);
            hst[hrow + t*20 + d] = h;                    // save hf[t]
            hxs[crow + 2*d] = h;                         // publish h for t+1
        }
    }

    // ---------------- backward scan ----------------
    {
        float wxi[9], wxf[9], wxg[9], wxo[9], whi[9], whf[9], whg[9], who[9];
        #pragma unroll
        for (int k = 0; k < 9; ++k) {
            wxi[k] = bWih[(d     )*9 + k];  whi[k] = bWhh[(d     )*9 + k];
            wxf[k] = bWih[(9  + d)*9 + k];  whf[k] = bWhh[(9  + d)*9 + k];
            wxg[k] = bWih[(18 + d)*9 + k];  whg[k] = bWhh[(18 + d)*9 + k];
            wxo[k] = bWih[(27 + d)*9 + k];  who[k] = bWhh[(27 + d)*9 + k];
        }
        const float bi = bbih[d]      + bbhh[d];
        const float bf = bbih[9 + d]  + bbhh[9 + d];
        const float bg = bbih[18 + d] + bbhh[18 + d];
        const float bo = bbih[27 + d] + bbhh[27 + d];

        hxs[crow + 2*d] = 0.f;                 // hb(T) = 0
        float h = 0.f, c = 0.f;
        for (int tt = T_ - 1; tt >= 0; --tt) {
            hxs[crow + 2*d + 1] = xb[tt*9 + d];          // publish x
            float gi = bi, gf = bf, gg = bg, go = bo;
            #pragma unroll
            for (int j = 0; j < 8; j += 2) {
                float4 v = *(const float4*)&hxs[crow + 2*j];
                gi = fmaf(v.x, whi[j], fmaf(v.y, wxi[j], gi));
                gf = fmaf(v.x, whf[j], fmaf(v.y, wxf[j], gf));
                gg = fmaf(v.x, whg[j], fmaf(v.y, wxg[j], gg));
                go = fmaf(v.x, who[j], fmaf(v.y, wxo[j], go));
                gi = fmaf(v.z, whi[j+1], fmaf(v.w, wxi[j+1], gi));
                gf = fmaf(v.z, whf[j+1], fmaf(v.w, wxf[j+1], gf));
                gg = fmaf(v.z, whg[j+1], fmaf(v.w, wxg[j+1], gg));
                go = fmaf(v.z, who[j+1], fmaf(v.w, wxo[j+1], go));
            }
            {
                float2 v = *(const float2*)&hxs[crow + 16];
                gi = fmaf(v.x, whi[8], fmaf(v.y, wxi[8], gi));
                gf = fmaf(v.x, whf[8], fmaf(v.y, wxf[8], gf));
                gg = fmaf(v.x, whg[8], fmaf(v.y, wxg[8], gg));
                go = fmaf(v.x, who[8], fmaf(v.y, wxo[8], go));
            }
            c = sigm(gf) * c + sigm(gi) * tanh_(gg);
            h = sigm(go) * tanh_(c);                     // hb[tt]
            hst[hrow + tt*20 + 10 + d] = h;              // save hb[tt]
            hxs[crow + 2*d] = h;                         // publish for tt-1
        }
    }

    // ---------------- deferred readout (wave-local items) ----------------
    // 140 items per wave: item -> (chain 0..6, t 0..19)
    #pragma unroll 1
    for (int rr = 0; rr < 3; ++rr) {
        const int item = rr * 64 + lane;
        if (item >= 140) break;
        const int ch = item / 20;
        const int t  = item - ch * 20;
        const int ci2 = blockIdx.x * CPB + wib * 7 + ch;
        if (ci2 >= NM_) continue;
        const int base = (wib * 8 + ch) * 404 + t * 20;

        float hf[9], hb[9];
        #pragma unroll
        for (int j = 0; j < 4; ++j) {
            float2 a = *(const float2*)&hst[base + 2*j];
            hf[2*j] = a.x; hf[2*j+1] = a.y;
            float2 b = *(const float2*)&hst[base + 10 + 2*j];
            hb[2*j] = b.x; hb[2*j+1] = b.y;
        }
        hf[8] = hst[base + 8];
        hb[8] = hst[base + 18];

        const int n2 = ci2 / M_;
        const int m2 = ci2 - n2 * M_;
        const float vi = (m2 < numrec[n2 * T_]) ? 1.f : 0.f;

        float q[9];
        #pragma unroll
        for (int dd = 0; dd < 9; ++dd) {
            float a = lr1b[dd];
            #pragma unroll
            for (int k = 0; k < 9; ++k) a = fmaf(hf[k], lr1W[dd*18 + k], a);
            #pragma unroll
            for (int k = 0; k < 9; ++k) a = fmaf(hb[k], lr1W[dd*18 + 9 + k], a);
            q[dd] = fmaxf(a, 0.f);
        }
        float* op = out + (size_t)((n2 * T_ + t) * M_ + m2) * 7;
        #pragma unroll
        for (int j = 0; j < 7; ++j) {
            float a = lr2b[j];
            #pragma unroll
            for (int k = 0; k < 9; ++k) a = fmaf(q[k], lr2W[j*9 + k], a);
            op[j] = a * vi;
        }
    }
}

extern "C" void kernel_launch(void* const* d_in, const int* in_sizes, int n_in,
                              void* d_out, int out_size, void* d_ws, size_t ws_size,
                              hipStream_t stream) {
    const float* nf    = (const float*)d_in[0];
    const float* pos   = (const float*)d_in[1];
    const float* am    = (const float*)d_in[2];
    const float* msgW  = (const float*)d_in[3];
    const float* msgb  = (const float*)d_in[4];
    const float* gWih  = (const float*)d_in[5];
    const float* gWhh  = (const float*)d_in[6];
    const float* gbih  = (const float*)d_in[7];
    const float* gbhh  = (const float*)d_in[8];
    const float* ro1W  = (const float*)d_in[9];
    const float* ro1b  = (const float*)d_in[10];
    const float* ro2W  = (const float*)d_in[11];
    const float* ro2b  = (const float*)d_in[12];
    const float* lfWih = (const float*)d_in[13];
    const float* lfWhh = (const float*)d_in[14];
    const float* lfbih = (const float*)d_in[15];
    const float* lfbhh = (const float*)d_in[16];
    const float* lbWih = (const float*)d_in[17];
    const float* lbWhh = (const float*)d_in[18];
    const float* lbbih = (const float*)d_in[19];
    const float* lbbhh = (const float*)d_in[20];
    const float* lr1W  = (const float*)d_in[21];
    const float* lr1b  = (const float*)d_in[22];
    const float* lr2W  = (const float*)d_in[23];
    const float* lr2b  = (const float*)d_in[24];
    const int* numrec  = (const int*)d_in[25];

    // ws: hidden [nm][t][d] fp32 = 35,389,440 B
    float* hid = (float*)d_ws;

    float* outp = (float*)d_out;           // pred_label
    float* out0 = (float*)d_out + NTM7_;   // pred_label0

    // A: 80 (n,t) per block (2 per lane) -> 2048 blocks
    k_gnn <<<NT_ / 80, 256, 0, stream>>>(nf, pos, am, msgW, msgb, gWih, gWhh,
                                         gbih, gbhh, ro1W, ro1b, ro2W, ro2b,
                                         numrec, hid, out0);
    // B: 14 chains per 128-thread block
    const int lgrid = (NM_ + CPB - 1) / CPB;
    k_lstm<<<lgrid, 128, 0, stream>>>(hid, lfWih, lfWhh, lfbih, lfbhh,
                                      lbWih, lbWhh, lbbih, lbbhh,
                                      lr1W, lr1b, lr2W, lr2b, numrec, outp);
}

// Round 8
// 291.488 us; speedup vs baseline: 2.5090x; 1.1088x over previous
//
#include <hip/hip_runtime.h>

#define N_    8192
#define T_    20
#define M_    6
#define D_    9
#define NM_   (N_*M_)        // 49152 LSTM chains
#define NT_   (N_*T_)        // 163840 GNN problems
#define NTM7_ (N_*T_*M_*7)   // 6881280 elements per output tensor

#define LOG2E 1.44269504088896f

typedef __attribute__((ext_vector_type(2))) float v2f;

// native-rate activations: v_exp_f32 + v_rcp_f32 (no IEEE div sequence)
__device__ __forceinline__ float sigm(float x){
    return __builtin_amdgcn_rcpf(1.f + __builtin_amdgcn_exp2f(-LOG2E * x));
}
__device__ __forceinline__ float tanh_(float x){
    return fmaf(2.f, __builtin_amdgcn_rcpf(1.f + __builtin_amdgcn_exp2f(-2.f*LOG2E * x)), -1.f);
}
__device__ __forceinline__ v2f splat(float s){ return (v2f){s, s}; }
__device__ __forceinline__ v2f sigm2(v2f x){ v2f r; r.x = sigm(x.x); r.y = sigm(x.y); return r; }
__device__ __forceinline__ v2f tanh2(v2f x){ v2f r; r.x = tanh_(x.x); r.y = tanh_(x.y); return r; }
__device__ __forceinline__ v2f relu2(v2f x){ v2f r; r.x = fmaxf(x.x,0.f); r.y = fmaxf(x.y,0.f); return r; }

// ---------------------------------------------------------------------------
// Kernel A: GNN, packed fp32 (v_pk_fma_f32), TWO (n,t) problems per lane.
// 64-thread (single-wave) blocks; 6 lanes per group, 10 groups/wave.
// msg gather via wave-synchronous LDS broadcast rows (NO bpermutes):
//   mbuf[g][d*6+i] (v2f), group stride 58 v2f (116 dwords: 16B-aligned reads,
//   bank offsets g*20 mod 32 -> max 2-way aliasing = free).
// DS ops/lane: 9 ds_write_b64 + 27 ds_read_b128 per iteration (was 216 bperm).
// ---------------------------------------------------------------------------
__global__ __launch_bounds__(64) void k_gnn(
    const float* __restrict__ nf,    // (N,T,M,3)
    const float* __restrict__ pos,   // (N,T,M,6)
    const float* __restrict__ am,    // (N,T,M,M)
    const float* __restrict__ msgW, const float* __restrict__ msgb,
    const float* __restrict__ gWih, const float* __restrict__ gWhh,
    const float* __restrict__ gbih, const float* __restrict__ gbhh,
    const float* __restrict__ ro1W, const float* __restrict__ ro1b,
    const float* __restrict__ ro2W, const float* __restrict__ ro2b,
    const int*   __restrict__ numrec,
    float* __restrict__ hid,         // [nm][t][d]
    float* __restrict__ out0)        // pred_label0 region
{
    __shared__ v2f mbuf[11 * 58];    // 5104 B; row 10 = dummy for lanes 60..63

    const int lane = threadIdx.x & 63;
    const int g    = lane / 6;                // group 0..9 valid (10 = idle lanes)
    const int i    = lane - g * 6;            // node index 0..5
    const int gB   = g * 58;                  // LDS row base (v2f units)
    const bool lactive = (lane < 60);

    const int wbase = blockIdx.x * 20;        // NT_ divisible by 20
    const int ntA = lactive ? (wbase + g)      : 0;
    const int ntB = lactive ? (wbase + 10 + g) : 0;
    const int nA = ntA / T_, tA = ntA - nA * T_;
    const int nB = ntB / T_, tB = ntB - nB * T_;

    // own node features: concat(nodes_feature, pos), packed A/B
    v2f s[D_];
    {
        const float* pA = nf + (size_t)ntA * 18 + i * 3;
        const float* pB = nf + (size_t)ntB * 18 + i * 3;
        #pragma unroll
        for (int k = 0; k < 3; ++k) { s[k].x = pA[k]; s[k].y = pB[k]; }
    }
    {
        const float2* pA = (const float2*)(pos + (size_t)ntA * 36 + i * 6);
        const float2* pB = (const float2*)(pos + (size_t)ntB * 36 + i * 6);
        #pragma unroll
        for (int k = 0; k < 3; ++k) {
            float2 a = pA[k], b = pB[k];
            s[3 + 2*k]     = (v2f){a.x, b.x};
            s[3 + 2*k + 1] = (v2f){a.y, b.y};
        }
    }
    v2f attr[M_];
    {
        const float2* pA = (const float2*)(am + (size_t)ntA * 36 + i * 6);
        const float2* pB = (const float2*)(am + (size_t)ntB * 36 + i * 6);
        #pragma unroll
        for (int k = 0; k < 3; ++k) {
            float2 a = pA[k], b = pB[k];
            attr[2*k]     = (v2f){a.x, b.x};
            attr[2*k + 1] = (v2f){a.y, b.y};
        }
    }
    const int nrA = numrec[nA * T_];
    const int nrB = numrec[nB * T_];
    #pragma unroll
    for (int q = 0; q < M_; ++q) {
        attr[q].x *= (q < nrA) ? 1.f : 0.f;
        attr[q].y *= (q < nrB) ? 1.f : 0.f;
    }
    v2f vmi; vmi.x = (i < nrA) ? 1.f : 0.f; vmi.y = (i < nrB) ? 1.f : 0.f;

    // two GRU message-passing iterations (packed)
    #pragma unroll
    for (int it = 0; it < 2; ++it) {
        // msg_i[d] for own node, publish to LDS row
        #pragma unroll
        for (int d = 0; d < D_; ++d) {
            v2f a = splat(msgb[d]);
            #pragma unroll
            for (int k = 0; k < D_; ++k) a += s[k] * msgW[d*9 + k];
            mbuf[gB + d*6 + i] = a;             // ds_write_b64, wave-synchronous
        }
        // gather: mm[d] = sum_q attr[q] * msg_q[d]  (3x ds_read_b128 per d)
        v2f mm[D_];
        #pragma unroll
        for (int d = 0; d < D_; ++d) {
            const float4* rp = (const float4*)&mbuf[gB + d*6];
            float4 p0 = rp[0], p1 = rp[1], p2 = rp[2];
            v2f a = attr[0] * (v2f){p0.x, p0.y};
            a += attr[1] * (v2f){p0.z, p0.w};
            a += attr[2] * (v2f){p1.x, p1.y};
            a += attr[3] * (v2f){p1.z, p1.w};
            a += attr[4] * (v2f){p2.x, p2.y};
            a += attr[5] * (v2f){p2.z, p2.w};
            mm[d] = a;
        }
        // gates: r,z need only gx+gh sum -> single accumulator
        v2f grz[18], gxn[9], ghn[9];
        #pragma unroll
        for (int j = 0; j < 18; ++j) {
            v2f a = splat(gbih[j] + gbhh[j]);
            #pragma unroll
            for (int k = 0; k < D_; ++k) {
                a += mm[k] * gWih[j*9 + k];
                a += s[k]  * gWhh[j*9 + k];
            }
            grz[j] = a;
        }
        #pragma unroll
        for (int j = 0; j < 9; ++j) {
            v2f ax = splat(gbih[18 + j]), ah = splat(gbhh[18 + j]);
            #pragma unroll
            for (int k = 0; k < D_; ++k) {
                ax += mm[k] * gWih[(18 + j)*9 + k];
                ah += s[k]  * gWhh[(18 + j)*9 + k];
            }
            gxn[j] = ax; ghn[j] = ah;
        }
        #pragma unroll
        for (int d = 0; d < D_; ++d) {
            v2f r  = sigm2(grz[d]);
            v2f z  = sigm2(grz[9 + d]);
            v2f nn = tanh2(gxn[d] + r * ghn[d]);
            s[d] = vmi * ((splat(1.f) - z) * nn + z * s[d]);
        }
    }

    // hidden -> ws [nm][t][d]
    if (lactive) {
        float* hpA = hid + (size_t)(nA * M_ + i) * (T_ * D_) + tA * D_;
        float* hpB = hid + (size_t)(nB * M_ + i) * (T_ * D_) + tB * D_;
        #pragma unroll
        for (int d = 0; d < D_; ++d) { hpA[d] = s[d].x; hpB[d] = s[d].y; }
    }

    // p0 readout
    v2f q9[D_];
    #pragma unroll
    for (int d = 0; d < D_; ++d) {
        v2f a = splat(ro1b[d]);
        #pragma unroll
        for (int k = 0; k < D_; ++k) a += s[k] * ro1W[d*9 + k];
        q9[d] = relu2(a);
    }
    if (lactive) {
        float* opA = out0 + (size_t)ntA * 42 + i * 7;
        float* opB = out0 + (size_t)ntB * 42 + i * 7;
        #pragma unroll
        for (int j = 0; j < 7; ++j) {
            v2f a = splat(ro2b[j]);
            #pragma unroll
            for (int k = 0; k < D_; ++k) a += q9[k] * ro2W[j*9 + k];
            a *= vmi;
            opA[j] = a.x; opB[j] = a.y;
        }
    }
}

// ---------------------------------------------------------------------------
// Kernel B: merged bidirectional LSTM + deferred fused readout.
// (unchanged — verified at R6)
// ---------------------------------------------------------------------------
#define CPB 14   // chains per block

__global__ __launch_bounds__(128) void k_lstm(
    const float* __restrict__ hid,   // [nm][t][d]
    const float* __restrict__ fWih, const float* __restrict__ fWhh,
    const float* __restrict__ fbih, const float* __restrict__ fbhh,
    const float* __restrict__ bWih, const float* __restrict__ bWhh,
    const float* __restrict__ bbih, const float* __restrict__ bbhh,
    const float* __restrict__ lr1W, const float* __restrict__ lr1b,
    const float* __restrict__ lr2W, const float* __restrict__ lr2b,
    const int*   __restrict__ numrec,
    float* __restrict__ out)         // pred_label region
{
    __shared__ float hst[16 * 404];  // 25856 B
    __shared__ float hxs[16 * 20];   //  1280 B

    const int lane = threadIdx.x & 63;
    const int wib  = threadIdx.x >> 6;         // 0..1
    const int grp0 = lane / 9;                 // 0..7 (7 == lane 63 only)
    const int d    = lane - grp0 * 9;
    const int row  = wib * 8 + grp0;           // LDS row; rows 7,15 are dummies
    const int grp  = (grp0 < 7) ? grp0 : 6;    // chain index for global mapping

    bool active = (lane < 63);
    int ci = blockIdx.x * CPB + wib * 7 + grp;
    active = active && (ci < NM_);
    const int nm = active ? ci : 0;

    const float* xb = hid + (size_t)nm * (T_ * D_);
    const int crow = row * 20;
    const int hrow = row * 404;

    // ---------------- forward scan ----------------
    {
        float wxi[9], wxf[9], wxg[9], wxo[9], whi[9], whf[9], whg[9], who[9];
        #pragma unroll
        for (int k = 0; k < 9; ++k) {
            wxi[k] = fWih[(d     )*9 + k];  whi[k] = fWhh[(d     )*9 + k];
            wxf[k] = fWih[(9  + d)*9 + k];  whf[k] = fWhh[(9  + d)*9 + k];
            wxg[k] = fWih[(18 + d)*9 + k];  whg[k] = fWhh[(18 + d)*9 + k];
            wxo[k] = fWih[(27 + d)*9 + k];  who[k] = fWhh[(27 + d)*9 + k];
        }
        const float bi = fbih[d]      + fbhh[d];
        const float bf = fbih[9 + d]  + fbhh[9 + d];
        const float bg = fbih[18 + d] + fbhh[18 + d];
        const float bo = fbih[27 + d] + fbhh[27 + d];

        hxs[crow + 2*d] = 0.f;                 // h(-1) = 0
        float h = 0.f, c = 0.f;
        for (int t = 0; t < T_; ++t) {
            hxs[crow + 2*d + 1] = xb[t*9 + d];           // publish x
            float gi = bi, gf = bf, gg = bg, go = bo;
            #pragma unroll
            for (int j = 0; j < 8; j += 2) {             // b128: (h,x,h,x)
                float4 v = *(const float4*)&hxs[crow + 2*j];
                gi = fmaf(v.x, whi[j], fmaf(v.y, wxi[j], gi));
                gf = fmaf(v.x, whf[j], fmaf(v.y, wxf[j], gf));
                gg = fmaf(v.x, whg[j], fmaf(v.y, wxg[j], gg));
                go = fmaf(v.x, who[j], fmaf(v.y, wxo[j], go));
                gi = fmaf(v.z, whi[j+1], fmaf(v.w, wxi[j+1], gi));
                gf = fmaf(v.z, whf[j+1], fmaf(v.w, wxf[j+1], gf));
                gg = fmaf(v.z, whg[j+1], fmaf(v.w, wxg[j+1], gg));
                go = fmaf(v.z, who[j+1], fmaf(v.w, wxo[j+1], go));
            }
            {
                float2 v = *(const float2*)&hxs[crow + 16];
                gi = fmaf(v.x, whi[8], fmaf(v.y, wxi[8], gi));
                gf = fmaf(v.x, whf[8], fmaf(v.y, wxf[8], gf));
                gg = fmaf(v.x, whg[8], fmaf(v.y, wxg[8], gg));
                go = fmaf(v.x, who[8], fmaf(v.y, wxo[8], go));
            }
            c = sigm(gf) * c + sigm(gi) * tanh_(gg);
            h = sigm(go) * tanh_(c);
            hst[hrow + t*20 + d] = h;                    // save hf[t]
            hxs[crow + 2*d] = h;                         // publish h for t+1
        }
    }

    // ---------------- backward scan ----------------
    {
        float wxi[9], wxf[9], wxg[9], wxo[9], whi[9], whf[9], whg[9], who[9];
        #pragma unroll
        for (int k = 0; k < 9; ++k) {
            wxi[k] = bWih[(d     )*9 + k];  whi[k] = bWhh[(d     )*9 + k];
            wxf[k] = bWih[(9  + d)*9 + k];  whf[k] = bWhh[(9  + d)*9 + k];
            wxg[k] = bWih[(18 + d)*9 + k];  whg[k] = bWhh[(18 + d)*9 + k];
            wxo[k] = bWih[(27 + d)*9 + k];  who[k] = bWhh[(27 + d)*9 + k];
        }
        const float bi = bbih[d]      + bbhh[d];
        const float bf = bbih[9 + d]  + bbhh[9 + d];
        const float bg = bbih[18 + d] + bbhh[18 + d];
        const float bo = bbih[27 + d] + bbhh[27 + d];

        hxs[crow + 2*d] = 0.f;                 // hb(T) = 0
        float h = 0.f, c = 0.f;
        for (int tt = T_ - 1; tt >= 0; --tt) {
            hxs[crow + 2*d + 1] = xb[tt*9 + d];          // publish x
            float gi = bi, gf = bf, gg = bg, go = bo;
            #pragma unroll
            for (int j = 0; j < 8; j += 2) {
                float4 v = *(const float4*)&hxs[crow + 2*j];
                gi = fmaf(v.x, whi[j], fmaf(v.y, wxi[j], gi));
                gf = fmaf(v.x, whf[j], fmaf(v.y, wxf[j], gf));
                gg = fmaf(v.x, whg[j], fmaf(v.y, wxg[j], gg));
                go = fmaf(v.x, who[j], fmaf(v.y, wxo[j], go));
                gi = fmaf(v.z, whi[j+1], fmaf(v.w, wxi[j+1], gi));
                gf = fmaf(v.z, whf[j+1], fmaf(v.w, wxf[j+1], gf));
                gg = fmaf(v.z, whg[j+1], fmaf(v.w, wxg[j+1], gg));
                go = fmaf(v.z, who[j+1], fmaf(v.w, wxo[j+1], go));
            }
            {
                float2 v = *(const float2*)&hxs[crow + 16];
                gi = fmaf(v.x, whi[8], fmaf(v.y, wxi[8], gi));
                gf = fmaf(v.x, whf[8], fmaf(v.y, wxf[8], gf));
                gg = fmaf(v.x, whg[8], fmaf(v.y, wxg[8], gg));
                go = fmaf(v.x, who[8], fmaf(v.y, wxo[8], go));
            }
            c = sigm(gf) * c + sigm(gi) * tanh_(gg);
            h = sigm(go) * tanh_(c);                     // hb[tt]
            hst[hrow + tt*20 + 10 + d] = h;              // save hb[tt]
            hxs[crow + 2*d] = h;                         // publish for tt-1
        }
    }

    // ---------------- deferred readout (wave-local items) ----------------
    // 140 items per wave: item -> (chain 0..6, t 0..19)
    #pragma unroll 1
    for (int rr = 0; rr < 3; ++rr) {
        const int item = rr * 64 + lane;
        if (item >= 140) break;
        const int ch = item / 20;
        const int t  = item - ch * 20;
        const int ci2 = blockIdx.x * CPB + wib * 7 + ch;
        if (ci2 >= NM_) continue;
        const int base = (wib * 8 + ch) * 404 + t * 20;

        float hf[9], hb[9];
        #pragma unroll
        for (int j = 0; j < 4; ++j) {
            float2 a = *(const float2*)&hst[base + 2*j];
            hf[2*j] = a.x; hf[2*j+1] = a.y;
            float2 b = *(const float2*)&hst[base + 10 + 2*j];
            hb[2*j] = b.x; hb[2*j+1] = b.y;
        }
        hf[8] = hst[base + 8];
        hb[8] = hst[base + 18];

        const int n2 = ci2 / M_;
        const int m2 = ci2 - n2 * M_;
        const float vi = (m2 < numrec[n2 * T_]) ? 1.f : 0.f;

        float q[9];
        #pragma unroll
        for (int dd = 0; dd < 9; ++dd) {
            float a = lr1b[dd];
            #pragma unroll
            for (int k = 0; k < 9; ++k) a = fmaf(hf[k], lr1W[dd*18 + k], a);
            #pragma unroll
            for (int k = 0; k < 9; ++k) a = fmaf(hb[k], lr1W[dd*18 + 9 + k], a);
            q[dd] = fmaxf(a, 0.f);
        }
        float* op = out + (size_t)((n2 * T_ + t) * M_ + m2) * 7;
        #pragma unroll
        for (int j = 0; j < 7; ++j) {
            float a = lr2b[j];
            #pragma unroll
            for (int k = 0; k < 9; ++k) a = fmaf(q[k], lr2W[j*9 + k], a);
            op[j] = a * vi;
        }
    }
}

extern "C" void kernel_launch(void* const* d_in, const int* in_sizes, int n_in,
                              void* d_out, int out_size, void* d_ws, size_t ws_size,
                              hipStream_t stream) {
    const float* nf    = (const float*)d_in[0];
    const float* pos   = (const float*)d_in[1];
    const float* am    = (const float*)d_in[2];
    const float* msgW  = (const float*)d_in[3];
    const float* msgb  = (const float*)d_in[4];
    const float* gWih  = (const float*)d_in[5];
    const float* gWhh  = (const float*)d_in[6];
    const float* gbih  = (const float*)d_in[7];
    const float* gbhh  = (const float*)d_in[8];
    const float* ro1W  = (const float*)d_in[9];
    const float* ro1b  = (const float*)d_in[10];
    const float* ro2W  = (const float*)d_in[11];
    const float* ro2b  = (const float*)d_in[12];
    const float* lfWih = (const float*)d_in[13];
    const float* lfWhh = (const float*)d_in[14];
    const float* lfbih = (const float*)d_in[15];
    const float* lfbhh = (const float*)d_in[16];
    const float* lbWih = (const float*)d_in[17];
    const float* lbWhh = (const float*)d_in[18];
    const float* lbbih = (const float*)d_in[19];
    const float* lbbhh = (const float*)d_in[20];
    const float* lr1W  = (const float*)d_in[21];
    const float* lr1b  = (const float*)d_in[22];
    const float* lr2W  = (const float*)d_in[23];
    const float* lr2b  = (const float*)d_in[24];
    const int* numrec  = (const int*)d_in[25];

    // ws: hidden [nm][t][d] fp32 = 35,389,440 B
    float* hid = (float*)d_ws;

    float* outp = (float*)d_out;           // pred_label
    float* out0 = (float*)d_out + NTM7_;   // pred_label0

    // A: 20 (n,t) per single-wave block (2 per lane) -> 8192 blocks
    k_gnn <<<NT_ / 20, 64, 0, stream>>>(nf, pos, am, msgW, msgb, gWih, gWhh,
                                        gbih, gbhh, ro1W, ro1b, ro2W, ro2b,
                                        numrec, hid, out0);
    // B: 14 chains per 128-thread block
    const int lgrid = (NM_ + CPB - 1) / CPB;
    k_lstm<<<lgrid, 128, 0, stream>>>(hid, lfWih, lfWhh, lfbih, lfbhh,
                                      lbWih, lbWhh, lbbih, lbbhh,
                                      lr1W, lr1b, lr2W, lr2b, numrec, outp);
}

// Round 9
// 287.863 us; speedup vs baseline: 2.5406x; 1.0126x over previous
//
#include <hip/hip_runtime.h>

#define N_    8192
#define T_    20
#define M_    6
#define D_    9
#define NM_   (N_*M_)        // 49152 LSTM chains
#define NMP_  (NM_/2)        // 24576 chain PAIRS
#define NT_   (N_*T_)        // 163840 GNN problems
#define NTM7_ (N_*T_*M_*7)   // 6881280 elements per output tensor

#define LOG2E 1.44269504088896f

typedef __attribute__((ext_vector_type(2))) float v2f;

// native-rate activations: v_exp_f32 + v_rcp_f32 (no IEEE div sequence)
__device__ __forceinline__ float sigm(float x){
    return __builtin_amdgcn_rcpf(1.f + __builtin_amdgcn_exp2f(-LOG2E * x));
}
__device__ __forceinline__ float tanh_(float x){
    return fmaf(2.f, __builtin_amdgcn_rcpf(1.f + __builtin_amdgcn_exp2f(-2.f*LOG2E * x)), -1.f);
}
__device__ __forceinline__ v2f splat(float s){ return (v2f){s, s}; }
__device__ __forceinline__ v2f sigm2(v2f x){ v2f r; r.x = sigm(x.x); r.y = sigm(x.y); return r; }
__device__ __forceinline__ v2f tanh2(v2f x){ v2f r; r.x = tanh_(x.x); r.y = tanh_(x.y); return r; }
__device__ __forceinline__ v2f relu2(v2f x){ v2f r; r.x = fmaxf(x.x,0.f); r.y = fmaxf(x.y,0.f); return r; }

// ---------------------------------------------------------------------------
// Kernel A: GNN (unchanged — verified at R8)
// ---------------------------------------------------------------------------
__global__ __launch_bounds__(64) void k_gnn(
    const float* __restrict__ nf,    // (N,T,M,3)
    const float* __restrict__ pos,   // (N,T,M,6)
    const float* __restrict__ am,    // (N,T,M,M)
    const float* __restrict__ msgW, const float* __restrict__ msgb,
    const float* __restrict__ gWih, const float* __restrict__ gWhh,
    const float* __restrict__ gbih, const float* __restrict__ gbhh,
    const float* __restrict__ ro1W, const float* __restrict__ ro1b,
    const float* __restrict__ ro2W, const float* __restrict__ ro2b,
    const int*   __restrict__ numrec,
    float* __restrict__ hid,         // [nm][t][d]
    float* __restrict__ out0)        // pred_label0 region
{
    __shared__ v2f mbuf[11 * 58];    // 5104 B; row 10 = dummy for lanes 60..63

    const int lane = threadIdx.x & 63;
    const int g    = lane / 6;
    const int i    = lane - g * 6;
    const int gB   = g * 58;
    const bool lactive = (lane < 60);

    const int wbase = blockIdx.x * 20;
    const int ntA = lactive ? (wbase + g)      : 0;
    const int ntB = lactive ? (wbase + 10 + g) : 0;
    const int nA = ntA / T_, tA = ntA - nA * T_;
    const int nB = ntB / T_, tB = ntB - nB * T_;

    v2f s[D_];
    {
        const float* pA = nf + (size_t)ntA * 18 + i * 3;
        const float* pB = nf + (size_t)ntB * 18 + i * 3;
        #pragma unroll
        for (int k = 0; k < 3; ++k) { s[k].x = pA[k]; s[k].y = pB[k]; }
    }
    {
        const float2* pA = (const float2*)(pos + (size_t)ntA * 36 + i * 6);
        const float2* pB = (const float2*)(pos + (size_t)ntB * 36 + i * 6);
        #pragma unroll
        for (int k = 0; k < 3; ++k) {
            float2 a = pA[k], b = pB[k];
            s[3 + 2*k]     = (v2f){a.x, b.x};
            s[3 + 2*k + 1] = (v2f){a.y, b.y};
        }
    }
    v2f attr[M_];
    {
        const float2* pA = (const float2*)(am + (size_t)ntA * 36 + i * 6);
        const float2* pB = (const float2*)(am + (size_t)ntB * 36 + i * 6);
        #pragma unroll
        for (int k = 0; k < 3; ++k) {
            float2 a = pA[k], b = pB[k];
            attr[2*k]     = (v2f){a.x, b.x};
            attr[2*k + 1] = (v2f){a.y, b.y};
        }
    }
    const int nrA = numrec[nA * T_];
    const int nrB = numrec[nB * T_];
    #pragma unroll
    for (int q = 0; q < M_; ++q) {
        attr[q].x *= (q < nrA) ? 1.f : 0.f;
        attr[q].y *= (q < nrB) ? 1.f : 0.f;
    }
    v2f vmi; vmi.x = (i < nrA) ? 1.f : 0.f; vmi.y = (i < nrB) ? 1.f : 0.f;

    #pragma unroll
    for (int it = 0; it < 2; ++it) {
        #pragma unroll
        for (int d = 0; d < D_; ++d) {
            v2f a = splat(msgb[d]);
            #pragma unroll
            for (int k = 0; k < D_; ++k) a += s[k] * msgW[d*9 + k];
            mbuf[gB + d*6 + i] = a;
        }
        v2f mm[D_];
        #pragma unroll
        for (int d = 0; d < D_; ++d) {
            const float4* rp = (const float4*)&mbuf[gB + d*6];
            float4 p0 = rp[0], p1 = rp[1], p2 = rp[2];
            v2f a = attr[0] * (v2f){p0.x, p0.y};
            a += attr[1] * (v2f){p0.z, p0.w};
            a += attr[2] * (v2f){p1.x, p1.y};
            a += attr[3] * (v2f){p1.z, p1.w};
            a += attr[4] * (v2f){p2.x, p2.y};
            a += attr[5] * (v2f){p2.z, p2.w};
            mm[d] = a;
        }
        v2f grz[18], gxn[9], ghn[9];
        #pragma unroll
        for (int j = 0; j < 18; ++j) {
            v2f a = splat(gbih[j] + gbhh[j]);
            #pragma unroll
            for (int k = 0; k < D_; ++k) {
                a += mm[k] * gWih[j*9 + k];
                a += s[k]  * gWhh[j*9 + k];
            }
            grz[j] = a;
        }
        #pragma unroll
        for (int j = 0; j < 9; ++j) {
            v2f ax = splat(gbih[18 + j]), ah = splat(gbhh[18 + j]);
            #pragma unroll
            for (int k = 0; k < D_; ++k) {
                ax += mm[k] * gWih[(18 + j)*9 + k];
                ah += s[k]  * gWhh[(18 + j)*9 + k];
            }
            gxn[j] = ax; ghn[j] = ah;
        }
        #pragma unroll
        for (int d = 0; d < D_; ++d) {
            v2f r  = sigm2(grz[d]);
            v2f z  = sigm2(grz[9 + d]);
            v2f nn = tanh2(gxn[d] + r * ghn[d]);
            s[d] = vmi * ((splat(1.f) - z) * nn + z * s[d]);
        }
    }

    if (lactive) {
        float* hpA = hid + (size_t)(nA * M_ + i) * (T_ * D_) + tA * D_;
        float* hpB = hid + (size_t)(nB * M_ + i) * (T_ * D_) + tB * D_;
        #pragma unroll
        for (int d = 0; d < D_; ++d) { hpA[d] = s[d].x; hpB[d] = s[d].y; }
    }

    v2f q9[D_];
    #pragma unroll
    for (int d = 0; d < D_; ++d) {
        v2f a = splat(ro1b[d]);
        #pragma unroll
        for (int k = 0; k < D_; ++k) a += s[k] * ro1W[d*9 + k];
        q9[d] = relu2(a);
    }
    if (lactive) {
        float* opA = out0 + (size_t)ntA * 42 + i * 7;
        float* opB = out0 + (size_t)ntB * 42 + i * 7;
        #pragma unroll
        for (int j = 0; j < 7; ++j) {
            v2f a = splat(ro2b[j]);
            #pragma unroll
            for (int k = 0; k < D_; ++k) a += q9[k] * ro2W[j*9 + k];
            a *= vmi;
            opA[j] = a.x; opB[j] = a.y;
        }
    }
}

// ---------------------------------------------------------------------------
// Kernel B: bidirectional LSTM, packed fp32 — TWO chains per lane (v2f).
// 64-thread single-wave blocks; 7 pairs/wave, 9 lanes/pair; lane 63 = dummy
// row 7. hxs4[pair][j] = {hA,hB,xA,xB} float4: one b128 broadcast feeds two
// pk-FMAs per gate. x prefetched one step ahead, published with h in one
// b128 write. hf/hb stored as v2f rows; deferred pair-item readout.
// ---------------------------------------------------------------------------
__global__ __launch_bounds__(64) void k_lstm(
    const float* __restrict__ hid,   // [nm][t][d]
    const float* __restrict__ fWih, const float* __restrict__ fWhh,
    const float* __restrict__ fbih, const float* __restrict__ fbhh,
    const float* __restrict__ bWih, const float* __restrict__ bWhh,
    const float* __restrict__ bbih, const float* __restrict__ bbhh,
    const float* __restrict__ lr1W, const float* __restrict__ lr1b,
    const float* __restrict__ lr2W, const float* __restrict__ lr2b,
    const int*   __restrict__ numrec,
    float* __restrict__ out)         // pred_label region
{
    __shared__ float4 hxs4[8 * 11];  //  1408 B: [row][j] {hA,hB,xA,xB}
    __shared__ v2f    hstv[8 * 381]; // 24384 B: [row][t*19 + d]=hf, [..+9+d]=hb

    const int lane = threadIdx.x & 63;
    const int grp0 = lane / 9;                 // 0..7 (7 == lane 63 only)
    const int d    = lane - grp0 * 9;
    const int row  = grp0;                     // row 7 = dummy

    bool active = (grp0 < 7);
    int pi = blockIdx.x * 7 + (active ? grp0 : 0);
    active = active && (pi < NMP_);
    const int pair = active ? pi : 0;
    const int cA = pair * 2, cB = cA + 1;

    const float* xbA = hid + (size_t)cA * (T_ * D_);
    const float* xbB = hid + (size_t)cB * (T_ * D_);
    const int xrow = row * 11;
    const int hrow = row * 381;

    // ---------------- forward scan ----------------
    {
        float wxi[9], wxf[9], wxg[9], wxo[9], whi[9], whf[9], whg[9], who[9];
        #pragma unroll
        for (int k = 0; k < 9; ++k) {
            wxi[k] = fWih[(d     )*9 + k];  whi[k] = fWhh[(d     )*9 + k];
            wxf[k] = fWih[(9  + d)*9 + k];  whf[k] = fWhh[(9  + d)*9 + k];
            wxg[k] = fWih[(18 + d)*9 + k];  whg[k] = fWhh[(18 + d)*9 + k];
            wxo[k] = fWih[(27 + d)*9 + k];  who[k] = fWhh[(27 + d)*9 + k];
        }
        const float bi = fbih[d]      + fbhh[d];
        const float bf = fbih[9 + d]  + fbhh[9 + d];
        const float bg = fbih[18 + d] + fbhh[18 + d];
        const float bo = fbih[27 + d] + fbhh[27 + d];

        hxs4[xrow + d] = make_float4(0.f, 0.f, xbA[d], xbB[d]);  // {h(-1), x0}
        v2f h = splat(0.f), c = splat(0.f);
        for (int t = 0; t < T_; ++t) {
            const float xnA = (t < T_-1) ? xbA[(t+1)*9 + d] : 0.f;
            const float xnB = (t < T_-1) ? xbB[(t+1)*9 + d] : 0.f;
            v2f gi = splat(bi), gf = splat(bf), gg = splat(bg), go = splat(bo);
            #pragma unroll
            for (int j = 0; j < 9; ++j) {
                float4 v = hxs4[xrow + j];                 // broadcast b128
                v2f hj = (v2f){v.x, v.y}, xj = (v2f){v.z, v.w};
                gi += hj * whi[j]; gi += xj * wxi[j];
                gf += hj * whf[j]; gf += xj * wxf[j];
                gg += hj * whg[j]; gg += xj * wxg[j];
                go += hj * who[j]; go += xj * wxo[j];
            }
            c = sigm2(gf) * c + sigm2(gi) * tanh2(gg);
            h = sigm2(go) * tanh2(c);
            hstv[hrow + t*19 + d] = h;                     // save hf[t]
            hxs4[xrow + d] = make_float4(h.x, h.y, xnA, xnB);  // {h_t, x_{t+1}}
        }
    }

    // ---------------- backward scan ----------------
    {
        float wxi[9], wxf[9], wxg[9], wxo[9], whi[9], whf[9], whg[9], who[9];
        #pragma unroll
        for (int k = 0; k < 9; ++k) {
            wxi[k] = bWih[(d     )*9 + k];  whi[k] = bWhh[(d     )*9 + k];
            wxf[k] = bWih[(9  + d)*9 + k];  whf[k] = bWhh[(9  + d)*9 + k];
            wxg[k] = bWih[(18 + d)*9 + k];  whg[k] = bWhh[(18 + d)*9 + k];
            wxo[k] = bWih[(27 + d)*9 + k];  who[k] = bWhh[(27 + d)*9 + k];
        }
        const float bi = bbih[d]      + bbhh[d];
        const float bf = bbih[9 + d]  + bbhh[9 + d];
        const float bg = bbih[18 + d] + bbhh[18 + d];
        const float bo = bbih[27 + d] + bbhh[27 + d];

        hxs4[xrow + d] = make_float4(0.f, 0.f, xbA[19*9 + d], xbB[19*9 + d]);
        v2f h = splat(0.f), c = splat(0.f);
        for (int tt = T_ - 1; tt >= 0; --tt) {
            const float xnA = (tt > 0) ? xbA[(tt-1)*9 + d] : 0.f;
            const float xnB = (tt > 0) ? xbB[(tt-1)*9 + d] : 0.f;
            v2f gi = splat(bi), gf = splat(bf), gg = splat(bg), go = splat(bo);
            #pragma unroll
            for (int j = 0; j < 9; ++j) {
                float4 v = hxs4[xrow + j];
                v2f hj = (v2f){v.x, v.y}, xj = (v2f){v.z, v.w};
                gi += hj * whi[j]; gi += xj * wxi[j];
                gf += hj * whf[j]; gf += xj * wxf[j];
                gg += hj * whg[j]; gg += xj * wxg[j];
                go += hj * who[j]; go += xj * wxo[j];
            }
            c = sigm2(gf) * c + sigm2(gi) * tanh2(gg);
            h = sigm2(go) * tanh2(c);                      // hb[tt]
            hstv[hrow + tt*19 + 9 + d] = h;                // save hb[tt]
            hxs4[xrow + d] = make_float4(h.x, h.y, xnA, xnB);
        }
    }

    // ---------------- deferred readout (wave-local pair-items) ----------------
    // 140 items per wave: item -> (pair 0..6, t 0..19); each item outputs
    // BOTH chains of the pair.
    #pragma unroll 1
    for (int rr = 0; rr < 3; ++rr) {
        const int item = rr * 64 + lane;
        if (item >= 140) break;
        const int ch = item / 20;
        const int t  = item - ch * 20;
        const int pi2 = blockIdx.x * 7 + ch;
        if (pi2 >= NMP_) continue;
        const int base = ch * 381 + t * 19;

        v2f hf[9], hb[9];
        #pragma unroll
        for (int k = 0; k < 9; ++k) { hf[k] = hstv[base + k]; hb[k] = hstv[base + 9 + k]; }

        const int cA2 = pi2 * 2, cB2 = cA2 + 1;
        const int nA2 = cA2 / M_, mA2 = cA2 - nA2 * M_;
        const int nB2 = cB2 / M_, mB2 = cB2 - nB2 * M_;
        v2f vi;
        vi.x = (mA2 < numrec[nA2 * T_]) ? 1.f : 0.f;
        vi.y = (mB2 < numrec[nB2 * T_]) ? 1.f : 0.f;

        v2f q[9];
        #pragma unroll
        for (int dd = 0; dd < 9; ++dd) {
            v2f a = splat(lr1b[dd]);
            #pragma unroll
            for (int k = 0; k < 9; ++k) a += hf[k] * lr1W[dd*18 + k];
            #pragma unroll
            for (int k = 0; k < 9; ++k) a += hb[k] * lr1W[dd*18 + 9 + k];
            q[dd] = relu2(a);
        }
        float* opA = out + (size_t)((nA2 * T_ + t) * M_ + mA2) * 7;
        float* opB = out + (size_t)((nB2 * T_ + t) * M_ + mB2) * 7;
        #pragma unroll
        for (int j = 0; j < 7; ++j) {
            v2f a = splat(lr2b[j]);
            #pragma unroll
            for (int k = 0; k < 9; ++k) a += q[k] * lr2W[j*9 + k];
            a *= vi;
            opA[j] = a.x; opB[j] = a.y;
        }
    }
}

extern "C" void kernel_launch(void* const* d_in, const int* in_sizes, int n_in,
                              void* d_out, int out_size, void* d_ws, size_t ws_size,
                              hipStream_t stream) {
    const float* nf    = (const float*)d_in[0];
    const float* pos   = (const float*)d_in[1];
    const float* am    = (const float*)d_in[2];
    const float* msgW  = (const float*)d_in[3];
    const float* msgb  = (const float*)d_in[4];
    const float* gWih  = (const float*)d_in[5];
    const float* gWhh  = (const float*)d_in[6];
    const float* gbih  = (const float*)d_in[7];
    const float* gbhh  = (const float*)d_in[8];
    const float* ro1W  = (const float*)d_in[9];
    const float* ro1b  = (const float*)d_in[10];
    const float* ro2W  = (const float*)d_in[11];
    const float* ro2b  = (const float*)d_in[12];
    const float* lfWih = (const float*)d_in[13];
    const float* lfWhh = (const float*)d_in[14];
    const float* lfbih = (const float*)d_in[15];
    const float* lfbhh = (const float*)d_in[16];
    const float* lbWih = (const float*)d_in[17];
    const float* lbWhh = (const float*)d_in[18];
    const float* lbbih = (const float*)d_in[19];
    const float* lbbhh = (const float*)d_in[20];
    const float* lr1W  = (const float*)d_in[21];
    const float* lr1b  = (const float*)d_in[22];
    const float* lr2W  = (const float*)d_in[23];
    const float* lr2b  = (const float*)d_in[24];
    const int* numrec  = (const int*)d_in[25];

    // ws: hidden [nm][t][d] fp32 = 35,389,440 B
    float* hid = (float*)d_ws;

    float* outp = (float*)d_out;           // pred_label
    float* out0 = (float*)d_out + NTM7_;   // pred_label0

    // A: 20 (n,t) per single-wave block (2 per lane) -> 8192 blocks
    k_gnn <<<NT_ / 20, 64, 0, stream>>>(nf, pos, am, msgW, msgb, gWih, gWhh,
                                        gbih, gbhh, ro1W, ro1b, ro2W, ro2b,
                                        numrec, hid, out0);
    // B: 7 chain-pairs per single-wave block -> ceil(24576/7) = 3511 blocks
    const int lgrid = (NMP_ + 6) / 7;
    k_lstm<<<lgrid, 64, 0, stream>>>(hid, lfWih, lfWhh, lfbih, lfbhh,
                                     lbWih, lbWhh, lbbih, lbbhh,
                                     lr1W, lr1b, lr2W, lr2b, numrec, outp);
}